// Round 2
// baseline (51761.804 us; speedup 1.0000x reference)
//
#include <hip/hip_runtime.h>

// LSTM fused kernel for MI355X (gfx950).
// Persistent kernel, 256 blocks (1/CU), weight-stationary fp16 MFMA.
// Per step t: z[256,4096] = [h_t | x_t] @ [Wh; Wx] (K=1280) via mfma_f32_16x16x32_f16,
// gates + c/h update fused, h exchanged via global double buffer with per-group
// (32-block) atomic barriers. c stays in LDS. Epilogue: logits + softmax.
// Workspace layout (~12.4 MB):
//   WT   fp16 [4096][1280]  (Wcat^T)      @ 0
//   WphT fp16 [256][1024]                 @ 10485760
//   hbuf fp16 [2][256][1024]              @ 11010048
//   lg   f32  [256][256]                  @ 12058624
//   cnt  u32  [8*16]                      @ 12320768

typedef _Float16 f16;
typedef _Float16 f16x8 __attribute__((ext_vector_type(8)));
typedef _Float16 f16x4 __attribute__((ext_vector_type(4)));
typedef float f32x4 __attribute__((ext_vector_type(4)));
typedef unsigned int u32;

#define WS_WT    0
#define WS_WPHT  10485760
#define WS_HBUF  11010048
#define WS_LG    12058624
#define WS_CNT   12320768

__device__ __forceinline__ float sigm(float v) { return 1.0f / (1.0f + __expf(-v)); }
__device__ __forceinline__ float tanhfast(float v) {
  float t = __expf(-2.0f * fabsf(v));
  float r = (1.0f - t) / (1.0f + t);
  return v < 0.0f ? -r : r;
}

// ---------- prep: WT[n][k], n=gate*1024+j (z-col), k in [0,1280): k<1024 -> Wh[k][j], else Wx[k-1024][j]
__global__ __launch_bounds__(256) void prep_wt(
    const float* __restrict__ Wgh, const float* __restrict__ Wih,
    const float* __restrict__ Wfh, const float* __restrict__ Woh,
    const float* __restrict__ Wgx, const float* __restrict__ Wix,
    const float* __restrict__ Wfx, const float* __restrict__ Wox,
    f16* __restrict__ WT)
{
  __shared__ float tile[32][33];
  int bid = blockIdx.x;
  int gate = bid / 1280;
  int rem  = bid % 1280;
  int jt = rem / 40, kt = rem % 40;
  const float* srcH = (gate==0)?Wgh:(gate==1)?Wih:(gate==2)?Wfh:Woh;
  const float* srcX = (gate==0)?Wgx:(gate==1)?Wix:(gate==2)?Wfx:Wox;
  const float* src = (kt < 32) ? (srcH + (size_t)(kt*32)*1024)
                               : (srcX + (size_t)(kt*32 - 1024)*1024);
  int t = threadIdx.x;
  {
    int jl = t & 31, kg = t >> 5;
#pragma unroll
    for (int it = 0; it < 4; ++it) {
      int kl = kg + it*8;
      tile[kl][jl] = src[(size_t)kl*1024 + jt*32 + jl];
    }
  }
  __syncthreads();
  {
    int kl = t & 31, jg = t >> 5;
#pragma unroll
    for (int it = 0; it < 4; ++it) {
      int jl2 = jg + it*8;
      WT[(size_t)(gate*1024 + jt*32 + jl2)*1280 + kt*32 + kl] = (f16)tile[kl][jl2];
    }
  }
}

// ---------- prep: WphT[oc][k] = W_ph[k][oc], fp16
__global__ __launch_bounds__(256) void prep_wph(const float* __restrict__ Wph,
                                                f16* __restrict__ WphT)
{
  __shared__ float tile[32][33];
  int bid = blockIdx.x;
  int jt = bid & 7, kt = bid >> 3;
  int t = threadIdx.x;
  {
    int jl = t & 31, kg = t >> 5;
#pragma unroll
    for (int it = 0; it < 4; ++it) {
      int kl = kg + it*8;
      tile[kl][jl] = Wph[(size_t)(kt*32 + kl)*256 + jt*32 + jl];
    }
  }
  __syncthreads();
  {
    int kl = t & 31, jg = t >> 5;
#pragma unroll
    for (int it = 0; it < 4; ++it) {
      int jl2 = jg + it*8;
      WphT[(size_t)(jt*32 + jl2)*1024 + kt*32 + kl] = (f16)tile[kl][jl2];
    }
  }
}

// ---------- main persistent LSTM kernel
// grid 256: block b -> r = b>>5 (batch tile of 32 rows), cg = b&31 (32 h-cols).
// 8 waves: cgrp = w&1 (which 64 of this block's 128 z-cols), kh = w>>1 (K-quarter of 1280).
// LDS: As (swizzled A tile) 0..81920, reduce slots alias 0..49152,
//      zbuf alias 49152..65536, cbuf persistent 81920..86016.
__global__ __launch_bounds__(512, 2) void lstm_main(
    const float* __restrict__ x, const f16* __restrict__ WT,
    const f16* __restrict__ WphT, f16* __restrict__ hbuf,
    const float* __restrict__ bgp, const float* __restrict__ bip,
    const float* __restrict__ bfp, const float* __restrict__ bop,
    const float* __restrict__ bpp, float* __restrict__ lg,
    u32* __restrict__ cnt, float* __restrict__ out)
{
  __shared__ __align__(16) char smem[86016];
  const int tid  = threadIdx.x;
  const int lane = tid & 63;
  const int wv   = tid >> 6;
  const int cgrp = wv & 1;
  const int kh   = wv >> 1;
  const int r    = blockIdx.x >> 5;
  const int cg   = blockIdx.x & 31;
  u32* myCnt = cnt + r*16;

  const int l15 = lane & 15, l4 = lane >> 4;

  // ---- weight-stationary B fragments (160 VGPR): Breg[kk][f]
  f16x8 Breg[10][4];
#pragma unroll
  for (int kk = 0; kk < 10; ++kk) {
    int k = kh*320 + kk*32 + l4*8;
#pragma unroll
    for (int f = 0; f < 4; ++f) {
      int j = cgrp*64 + f*16 + l15;                 // local z-col 0..127
      int n = (j >> 5)*1024 + cg*32 + (j & 31);     // global z-col
      Breg[kk][f] = *(const f16x8*)(WT + (size_t)n*1280 + k);
    }
  }

  // A-frag LDS addressing: addr = (row*2560 + kb + kk*64) ^ ((row&7)<<4)
  // XOR applied PER ACCESS (after adding kk*64) to match the staging writes.
  // row1 = row0+16 shares the same swizzle value ((row+16)&7 == row&7).
  u32 aoff0, aoff1, aswz;
  {
    u32 row0 = (u32)l15;
    u32 kb = (u32)(kh*320 + l4*8) * 2u;
    aoff0 = row0*2560u + kb;
    aoff1 = aoff0 + 16u*2560u;
    aswz  = ((u32)(l15 & 7)) << 4;
  }

  // staging indices
  const int srow = tid >> 4;
  const int sseg = tid & 15;
  const u32 swzr = ((u32)(srow & 7) << 4);
  const int grow = r*32 + srow;

  // zero c
#pragma unroll
  for (int e = 0; e < 2; ++e)
    *(float*)(smem + 81920 + (tid + e*512)*4) = 0.0f;

#pragma unroll 1
  for (int s = 0; s < 512; ++s) {
    if (s > 0) {
      if (tid == 0) {
        u32 tgt = (u32)(32*s);
        int guard = 0;
        while (__hip_atomic_load(myCnt, __ATOMIC_ACQUIRE, __HIP_MEMORY_SCOPE_AGENT) < tgt) {
          __builtin_amdgcn_s_sleep(2);
          if (++guard > (1 << 26)) break;
        }
      }
      __syncthreads();
      __threadfence();   // acquire side: invalidate stale h lines (cross-XCD)
    }
    // ---- stage A tile [32 rows x 1280] fp16, XOR-swizzled
    {
      const f16* hsrc = hbuf + (size_t)(s & 1)*262144 + (size_t)grow*1024;
#pragma unroll
      for (int j = 0; j < 8; ++j) {
        int chunk = sseg + 16*j;                       // 16B chunk of h row
        uint4 v = *(const uint4*)(hsrc + chunk*8);
        *(uint4*)(smem + ((srow*2560u + 16u*(u32)chunk) ^ swzr)) = v;
      }
      const float* xsrc = x + ((size_t)grow*512 + (size_t)s)*256;
#pragma unroll
      for (int j = 0; j < 4; ++j) {
        int chunk = sseg + 16*j;                       // float4 chunk of x row
        float4 v = *(const float4*)(xsrc + chunk*4);
        f16x4 hv;
        hv[0] = (f16)v.x; hv[1] = (f16)v.y; hv[2] = (f16)v.z; hv[3] = (f16)v.w;
        *(f16x4*)(smem + ((srow*2560u + 2048u + 8u*(u32)chunk) ^ swzr)) = hv;
      }
    }
    __syncthreads();
    // ---- K loop: z partial = A * B over this wave's K window
    f32x4 acc0[4], acc1[4];
#pragma unroll
    for (int f = 0; f < 4; ++f) { acc0[f] = {}; acc1[f] = {}; }
#pragma unroll
    for (int kk = 0; kk < 10; ++kk) {
      f16x8 av0 = *(const f16x8*)(smem + ((aoff0 + (u32)kk*64u) ^ aswz));
      f16x8 av1 = *(const f16x8*)(smem + ((aoff1 + (u32)kk*64u) ^ aswz));
#pragma unroll
      for (int f = 0; f < 4; ++f) {
        acc0[f] = __builtin_amdgcn_mfma_f32_16x16x32_f16(av0, Breg[kk][f], acc0[f], 0, 0, 0);
        acc1[f] = __builtin_amdgcn_mfma_f32_16x16x32_f16(av1, Breg[kk][f], acc1[f], 0, 0, 0);
      }
    }
    __syncthreads();
    // ---- cross-kh reduction (4 partials) via LDS
    if (kh > 0) {
      u32 base = (u32)((kh-1)*2 + cgrp) * 8192u;
#pragma unroll
      for (int f = 0; f < 4; ++f) {
        *(f32x4*)(smem + base + (u32)((0*4 + f)*64 + lane)*16u) = acc0[f];
        *(f32x4*)(smem + base + (u32)((1*4 + f)*64 + lane)*16u) = acc1[f];
      }
    }
    __syncthreads();
    if (kh == 0) {
#pragma unroll
      for (int ss = 0; ss < 3; ++ss) {
        u32 base = (u32)(ss*2 + cgrp) * 8192u;
#pragma unroll
        for (int f = 0; f < 4; ++f) {
          acc0[f] += *(const f32x4*)(smem + base + (u32)((0*4 + f)*64 + lane)*16u);
          acc1[f] += *(const f32x4*)(smem + base + (u32)((1*4 + f)*64 + lane)*16u);
        }
      }
      // write z to zbuf[gate][row][col]
#pragma unroll
      for (int f = 0; f < 4; ++f) {
        int gate = cgrp*2 + (f >> 1);
        int col  = (f & 1)*16 + l15;
#pragma unroll
        for (int i = 0; i < 4; ++i) {
          int row0 = l4*4 + i;
          *(float*)(smem + 49152u + (u32)((gate*32 + row0     )*32 + col)*4u) = acc0[f][i];
          *(float*)(smem + 49152u + (u32)((gate*32 + row0 + 16)*32 + col)*4u) = acc1[f][i];
        }
      }
    }
    __syncthreads();
    // ---- gates + c/h update (all 512 threads, 2 elems each)
    {
      f16* hw = hbuf + (size_t)((s & 1) ^ 1)*262144;
#pragma unroll
      for (int e2 = 0; e2 < 2; ++e2) {
        int e = tid + e2*512;
        int row = e >> 5, col = e & 31;
        int gcol = cg*32 + col;
        float zg = *(const float*)(smem + 49152u + (u32)(0*1024 + row*32 + col)*4u) + bgp[gcol];
        float zi = *(const float*)(smem + 49152u + (u32)(1*1024 + row*32 + col)*4u) + bip[gcol];
        float zf = *(const float*)(smem + 49152u + (u32)(2*1024 + row*32 + col)*4u) + bfp[gcol];
        float zo = *(const float*)(smem + 49152u + (u32)(3*1024 + row*32 + col)*4u) + bop[gcol];
        float* cp = (float*)(smem + 81920u + (u32)(row*32 + col)*4u);
        float cv = *cp;
        float gv = tanhfast(zg);
        float iv = sigm(zi);
        float fv = sigm(zf);
        float ov = sigm(zo);
        float cn = gv*iv + cv*fv;
        *cp = cn;
        float hv = tanhfast(cn) * ov;
        hw[(size_t)(r*32 + row)*1024 + gcol] = (f16)hv;
      }
    }
    __threadfence();   // release side: make h visible agent-wide
    __syncthreads();
    if (tid == 0) __hip_atomic_fetch_add(myCnt, 1u, __ATOMIC_RELEASE, __HIP_MEMORY_SCOPE_AGENT);
  }

  // ---- epilogue: wait group, logits = h @ WphT + bp
  if (tid == 0) {
    int guard = 0;
    while (__hip_atomic_load(myCnt, __ATOMIC_ACQUIRE, __HIP_MEMORY_SCOPE_AGENT) < 32u*512u) {
      __builtin_amdgcn_s_sleep(2);
      if (++guard > (1 << 26)) break;
    }
  }
  __syncthreads();
  __threadfence();
  {
#pragma unroll 1
    for (int p = 0; p < 32; ++p) {
      int rowl = wv*4 + (p >> 3);
      int oc   = p & 7;
      const f16* hp = hbuf + (size_t)(r*32 + rowl)*1024 + lane*16;   // buffer 0 holds h_T
      const f16* wp = WphT + (size_t)(cg*8 + oc)*1024 + lane*16;
      f16x8 h0 = *(const f16x8*)hp;
      f16x8 h1 = *(const f16x8*)(hp + 8);
      f16x8 w0 = *(const f16x8*)wp;
      f16x8 w1 = *(const f16x8*)(wp + 8);
      float sum = 0.f;
#pragma unroll
      for (int q = 0; q < 8; ++q)
        sum += (float)h0[q]*(float)w0[q] + (float)h1[q]*(float)w1[q];
#pragma unroll
      for (int d = 1; d < 64; d <<= 1) sum += __shfl_xor(sum, d);
      if (lane == 0)
        lg[(size_t)(r*32 + rowl)*256 + cg*8 + oc] = sum + bpp[cg*8 + oc];
    }
  }
  __threadfence();
  __syncthreads();
  if (tid == 0) {
    __hip_atomic_fetch_add(myCnt, 1u, __ATOMIC_RELEASE, __HIP_MEMORY_SCOPE_AGENT);
    int guard = 0;
    while (__hip_atomic_load(myCnt, __ATOMIC_ACQUIRE, __HIP_MEMORY_SCOPE_AGENT) < 32u*512u + 32u) {
      __builtin_amdgcn_s_sleep(2);
      if (++guard > (1 << 26)) break;
    }
  }
  __syncthreads();
  __threadfence();
  // ---- softmax: block handles row r*32+cg, wave 0 only
  if (tid < 64) {
    int rowg = r*32 + cg;
    const float* lr = lg + (size_t)rowg*256;
    float v0 = lr[tid], v1 = lr[tid+64], v2 = lr[tid+128], v3 = lr[tid+192];
    float mx = fmaxf(fmaxf(v0, v1), fmaxf(v2, v3));
#pragma unroll
    for (int d = 1; d < 64; d <<= 1) mx = fmaxf(mx, __shfl_xor(mx, d));
    float e0 = __expf(v0-mx), e1 = __expf(v1-mx), e2 = __expf(v2-mx), e3 = __expf(v3-mx);
    float sm = e0+e1+e2+e3;
#pragma unroll
    for (int d = 1; d < 64; d <<= 1) sm += __shfl_xor(sm, d);
    float inv = 1.0f / sm;
    float* orow = out + (size_t)rowg*256;
    orow[tid]      = e0*inv;
    orow[tid+64]   = e1*inv;
    orow[tid+128]  = e2*inv;
    orow[tid+192]  = e3*inv;
  }
}

extern "C" void kernel_launch(void* const* d_in, const int* in_sizes, int n_in,
                              void* d_out, int out_size, void* d_ws, size_t ws_size,
                              hipStream_t stream) {
  (void)in_sizes; (void)n_in; (void)out_size; (void)ws_size;
  const float* x   = (const float*)d_in[0];
  const float* Wgx = (const float*)d_in[1];
  const float* Wgh = (const float*)d_in[2];
  const float* bg  = (const float*)d_in[3];
  const float* Wix = (const float*)d_in[4];
  const float* Wih = (const float*)d_in[5];
  const float* bi  = (const float*)d_in[6];
  const float* Wfx = (const float*)d_in[7];
  const float* Wfh = (const float*)d_in[8];
  const float* bf  = (const float*)d_in[9];
  const float* Wox = (const float*)d_in[10];
  const float* Woh = (const float*)d_in[11];
  const float* bo  = (const float*)d_in[12];
  const float* Wph = (const float*)d_in[13];
  const float* bp  = (const float*)d_in[14];

  char* ws = (char*)d_ws;
  f16*   WT   = (f16*)(ws + WS_WT);
  f16*   WphT = (f16*)(ws + WS_WPHT);
  f16*   hbuf = (f16*)(ws + WS_HBUF);
  float* lg   = (float*)(ws + WS_LG);
  u32*   cnt  = (u32*)(ws + WS_CNT);

  // h0 = 0 (buffer 0) and barrier counters = 0, every call (replay-safe)
  hipMemsetAsync(hbuf, 0, 524288, stream);
  hipMemsetAsync(cnt, 0, 512, stream);

  prep_wt<<<5120, 256, 0, stream>>>(Wgh, Wih, Wfh, Woh, Wgx, Wix, Wfx, Wox, WT);
  prep_wph<<<256, 256, 0, stream>>>(Wph, WphT);
  lstm_main<<<256, 512, 0, stream>>>(x, WT, WphT, hbuf,
                                     bg, bi, bf, bo, bp,
                                     lg, cnt, (float*)d_out);
}

// Round 3
// 11729.448 us; speedup vs baseline: 4.4130x; 4.4130x over previous
//
#include <hip/hip_runtime.h>

// LSTM fused kernel for MI355X (gfx950) — round 2: XCD-local barrier redesign.
// Persistent kernel, 256 blocks (1/CU), weight-stationary fp16 MFMA.
// Group = bid&7 (32 blocks; XCD-local if dispatch round-robins; detected at runtime).
// Per step: z[32,128] per block = [h|x] @ W-slice (K=1280), col-split across 8 waves
// (16 z-cols × full K each, no cross-wave reduction). h exchanged via global double
// buffer; sync via per-block flag stores + wave0 coalesced poll (no RMW, no
// thread-wide fences). Cheap path: L1 inv only. Fallback: 1-thread threadfence.
// Workspace (~12.4 MB):
//   WT   fp16 [4096][1280]  @ 0          WphT fp16 [256][1024] @ 10485760
//   hbuf fp16 [2][256][1024] @ 11010048  lg f32 [256][256] @ 12058624
//   cnt  u32 [8][32] @ 12320768          xcdtab u32 [8][32] @ 12321792

typedef _Float16 f16;
typedef _Float16 f16x8 __attribute__((ext_vector_type(8)));
typedef _Float16 f16x4 __attribute__((ext_vector_type(4)));
typedef float f32x4 __attribute__((ext_vector_type(4)));
typedef unsigned int u32;

#define WS_WT    0
#define WS_WPHT  10485760
#define WS_HBUF  11010048
#define WS_LG    12058624
#define WS_CNT   12320768
#define WS_XCD   12321792

__device__ __forceinline__ float sigm(float v) { return 1.0f / (1.0f + __expf(-v)); }
__device__ __forceinline__ float tanhfast(float v) {
  float t = __expf(-2.0f * fabsf(v));
  float r = (1.0f - t) / (1.0f + t);
  return v < 0.0f ? -r : r;
}

// ---------- prep: WT[n][k], n=gate*1024+j (z-col), k<1024 -> Wh[k][j], else Wx[k-1024][j]
__global__ __launch_bounds__(256) void prep_wt(
    const float* __restrict__ Wgh, const float* __restrict__ Wih,
    const float* __restrict__ Wfh, const float* __restrict__ Woh,
    const float* __restrict__ Wgx, const float* __restrict__ Wix,
    const float* __restrict__ Wfx, const float* __restrict__ Wox,
    f16* __restrict__ WT)
{
  __shared__ float tile[32][33];
  int bid = blockIdx.x;
  int gate = bid / 1280;
  int rem  = bid % 1280;
  int jt = rem / 40, kt = rem % 40;
  const float* srcH = (gate==0)?Wgh:(gate==1)?Wih:(gate==2)?Wfh:Woh;
  const float* srcX = (gate==0)?Wgx:(gate==1)?Wix:(gate==2)?Wfx:Wox;
  const float* src = (kt < 32) ? (srcH + (size_t)(kt*32)*1024)
                               : (srcX + (size_t)(kt*32 - 1024)*1024);
  int t = threadIdx.x;
  {
    int jl = t & 31, kg = t >> 5;
#pragma unroll
    for (int it = 0; it < 4; ++it) {
      int kl = kg + it*8;
      tile[kl][jl] = src[(size_t)kl*1024 + jt*32 + jl];
    }
  }
  __syncthreads();
  {
    int kl = t & 31, jg = t >> 5;
#pragma unroll
    for (int it = 0; it < 4; ++it) {
      int jl2 = jg + it*8;
      WT[(size_t)(gate*1024 + jt*32 + jl2)*1280 + kt*32 + kl] = (f16)tile[kl][jl2];
    }
  }
}

// ---------- prep: WphT[oc][k] = W_ph[k][oc], fp16
__global__ __launch_bounds__(256) void prep_wph(const float* __restrict__ Wph,
                                                f16* __restrict__ WphT)
{
  __shared__ float tile[32][33];
  int bid = blockIdx.x;
  int jt = bid & 7, kt = bid >> 3;
  int t = threadIdx.x;
  {
    int jl = t & 31, kg = t >> 5;
#pragma unroll
    for (int it = 0; it < 4; ++it) {
      int kl = kg + it*8;
      tile[kl][jl] = Wph[(size_t)(kt*32 + kl)*256 + jt*32 + jl];
    }
  }
  __syncthreads();
  {
    int kl = t & 31, jg = t >> 5;
#pragma unroll
    for (int it = 0; it < 4; ++it) {
      int jl2 = jg + it*8;
      WphT[(size_t)(jt*32 + jl2)*1024 + kt*32 + kl] = (f16)tile[kl][jl2];
    }
  }
}

// ---------- main persistent LSTM kernel
// LDS: A-tile (swizzled) 0..81920, zbuf [4][32][32]f32 81920..98304,
//      c [32][32]f32 98304..102400, xloc flag @102400.
__global__ __launch_bounds__(512, 2) void lstm_main(
    const float* __restrict__ x, const f16* __restrict__ WT,
    const f16* __restrict__ WphT, f16* __restrict__ hbuf,
    const float* __restrict__ bgp, const float* __restrict__ bip,
    const float* __restrict__ bfp, const float* __restrict__ bop,
    const float* __restrict__ bpp, float* __restrict__ lg,
    u32* __restrict__ cnt, u32* __restrict__ xcdtab, float* __restrict__ out)
{
  __shared__ __align__(16) char smem[102416];
  const int tid  = threadIdx.x;
  const int lane = tid & 63;
  const int wv   = tid >> 6;
  const int gate = wv >> 1;        // wave's gate (0..3)
  const int half = wv & 1;         // wave's 16-col half within gate
  const int xg   = blockIdx.x & 7; // group (batch tile) — XCD-local if round-robin
  const int cg   = blockIdx.x >> 3;// column slice 0..31
  const int l15 = lane & 15, l4 = lane >> 4;
  u32* flg = cnt + xg*32;

  // announce XCD (value+1 so 0 means "unset")
  u32 myxcd;
  asm volatile("s_getreg_b32 %0, hwreg(HW_REG_XCC_ID)" : "=s"(myxcd));
  if (tid == 0)
    __hip_atomic_store(xcdtab + xg*32 + cg, myxcd + 1u,
                       __ATOMIC_RELAXED, __HIP_MEMORY_SCOPE_AGENT);

  // ---- weight-stationary B fragments: 40 x f16x8 = 160 VGPR
  f16x8 Breg[40];
  {
    const int ncol = gate*1024 + cg*32 + half*16 + l15;   // global z-col
    const f16* wb = WT + (size_t)ncol*1280 + l4*8;
#pragma unroll
    for (int kk = 0; kk < 40; ++kk)
      Breg[kk] = *(const f16x8*)(wb + kk*32);
  }

  // per-thread bias (gate phase handles col = tid&31)
  const int bcol = cg*32 + (tid & 31);
  const float bgr = bgp[bcol], bir = bip[bcol], bfr = bfp[bcol], bor = bop[bcol];

  // A-frag addressing: addr = (row*2560 + l4*16 + kk*64) ^ ((row&7)<<4)
  u32 aoff0, aoff1, aswz;
  {
    aoff0 = (u32)l15*2560u + (u32)(l4*16);
    aoff1 = aoff0 + 16u*2560u;
    aswz  = ((u32)(l15 & 7)) << 4;
  }
  // staging indices
  const int srow = tid >> 4;
  const int sseg = tid & 15;
  const u32 swzr = ((u32)(srow & 7) << 4);
  const int grow = xg*32 + srow;

  // zero c
  *(float*)(smem + 98304 + tid*4) = 0.0f;
  *(float*)(smem + 98304 + (tid + 512)*4) = 0.0f;

  // ---- XCD-locality detection (wave 0), result broadcast via LDS
  if (wv == 0) {
    u32 ref = myxcd + 1u, v = ref;
    int guard = 0;
    for (;;) {
      if (lane < 32)
        v = __hip_atomic_load(xcdtab + xg*32 + lane,
                              __ATOMIC_RELAXED, __HIP_MEMORY_SCOPE_AGENT);
      if (__all(v != 0u)) break;
      __builtin_amdgcn_s_sleep(1);
      if (++guard > (1 << 24)) break;
    }
    int same = __all(v == ref);
    if (lane == 0) *(volatile u32*)(smem + 102400) = (u32)same;
  }
  __syncthreads();
  const bool xloc = (*(volatile u32*)(smem + 102400)) != 0u;

#pragma unroll 1
  for (int s = 0; s < 512; ++s) {
    // ---- group barrier: wait for all 32 blocks to have finished step s-1
    if (s > 0) {
      if (wv == 0) {
        const u32 tgt = (u32)s;
        u32 v = tgt;
        int guard = 0;
        for (;;) {
          if (lane < 32)
            v = __hip_atomic_load(flg + lane, __ATOMIC_RELAXED, __HIP_MEMORY_SCOPE_AGENT);
          if (__all(v >= tgt)) break;
          __builtin_amdgcn_s_sleep(1);
          if (++guard > (1 << 24)) break;
        }
        if (lane == 0) {
          if (xloc) { asm volatile("buffer_inv sc0" ::: "memory"); }  // L1 only
          else      { __threadfence(); }                              // L2 wb+inv
        }
      }
      __syncthreads();
    }
    // ---- stage A tile [32 rows x 1280] fp16, XOR-swizzled
    {
      const f16* hsrc = hbuf + (size_t)(s & 1)*262144 + (size_t)grow*1024;
#pragma unroll
      for (int j = 0; j < 8; ++j) {
        int chunk = sseg + 16*j;                       // 16B chunk of h row
        uint4 v = *(const uint4*)(hsrc + chunk*8);
        *(uint4*)(smem + ((srow*2560u + 16u*(u32)chunk) ^ swzr)) = v;
      }
      const float* xsrc = x + ((size_t)grow*512 + (size_t)s)*256;
#pragma unroll
      for (int j = 0; j < 4; ++j) {
        int chunk = sseg + 16*j;                       // float4 chunk of x row
        float4 v = *(const float4*)(xsrc + chunk*4);
        f16x4 hv;
        hv[0] = (f16)v.x; hv[1] = (f16)v.y; hv[2] = (f16)v.z; hv[3] = (f16)v.w;
        *(f16x4*)(smem + ((srow*2560u + 2048u + 8u*(u32)chunk) ^ swzr)) = hv;
      }
    }
    __syncthreads();
    // ---- K loop: full K=1280 per wave, 16 z-cols
    f32x4 acc0 = {}, acc1 = {};
#pragma unroll
    for (int kk = 0; kk < 40; ++kk) {
      f16x8 av0 = *(const f16x8*)(smem + ((aoff0 + (u32)kk*64u) ^ aswz));
      f16x8 av1 = *(const f16x8*)(smem + ((aoff1 + (u32)kk*64u) ^ aswz));
      acc0 = __builtin_amdgcn_mfma_f32_16x16x32_f16(av0, Breg[kk], acc0, 0, 0, 0);
      acc1 = __builtin_amdgcn_mfma_f32_16x16x32_f16(av1, Breg[kk], acc1, 0, 0, 0);
    }
    // write z to zbuf[gate][row][col] (wave-private region, no pre-sync needed)
    {
      const u32 zb = 81920u + (u32)(gate*1024 + half*16 + l15)*4u;
#pragma unroll
      for (int i = 0; i < 4; ++i) {
        u32 r0 = (u32)(l4*4 + i);
        *(float*)(smem + zb + r0*128u)         = acc0[i];
        *(float*)(smem + zb + (r0 + 16u)*128u) = acc1[i];
      }
    }
    __syncthreads();
    // ---- gates + c/h update (512 threads, rows tid>>5 and +16, col tid&31)
    {
      f16* hw = hbuf + (size_t)((s & 1) ^ 1)*262144;
      const int row = tid >> 5, col = tid & 31;
      const int gcol = cg*32 + col;
#pragma unroll
      for (int e2 = 0; e2 < 2; ++e2) {
        const int rr = row + e2*16;
        const u32 zo = (u32)(rr*128 + col*4);
        float zg = *(const float*)(smem + 81920u +        zo) + bgr;
        float zi = *(const float*)(smem + 81920u + 4096u + zo) + bir;
        float zf = *(const float*)(smem + 81920u + 8192u + zo) + bfr;
        float zv = *(const float*)(smem + 81920u + 12288u + zo) + bor;
        float* cp = (float*)(smem + 98304u + (u32)(rr*32 + col)*4u);
        float cv = *cp;
        float gv = tanhfast(zg);
        float iv = sigm(zi);
        float fv = sigm(zf);
        float ov = sigm(zv);
        float cn = gv*iv + cv*fv;
        *cp = cn;
        hw[(size_t)(xg*32 + rr)*1024 + gcol] = (f16)(tanhfast(cn) * ov);
      }
    }
    __syncthreads();   // drains all waves' vmcnt before flag release
    if (tid == 0) {
      if (!xloc) __threadfence();
      __hip_atomic_store(flg + cg, (u32)(s + 1),
                         __ATOMIC_RELAXED, __HIP_MEMORY_SCOPE_AGENT);
    }
  }

  // ---- epilogue: wait for whole group at step 512, then logits = h @ WphT + bp
  if (wv == 0) {
    u32 v = 512u;
    int guard = 0;
    for (;;) {
      if (lane < 32)
        v = __hip_atomic_load(flg + lane, __ATOMIC_RELAXED, __HIP_MEMORY_SCOPE_AGENT);
      if (__all(v >= 512u)) break;
      __builtin_amdgcn_s_sleep(1);
      if (++guard > (1 << 24)) break;
    }
    if (lane == 0) {
      if (xloc) { asm volatile("buffer_inv sc0" ::: "memory"); }
      else      { __threadfence(); }
    }
  }
  __syncthreads();
  {
#pragma unroll 1
    for (int p = 0; p < 32; ++p) {
      int rowl = wv*4 + (p >> 3);
      int oc   = p & 7;
      const f16* hp = hbuf + (size_t)(xg*32 + rowl)*1024 + lane*16;  // buf 0 = h_T
      const f16* wp = WphT + (size_t)(cg*8 + oc)*1024 + lane*16;
      f16x8 h0 = *(const f16x8*)hp;
      f16x8 h1 = *(const f16x8*)(hp + 8);
      f16x8 w0 = *(const f16x8*)wp;
      f16x8 w1 = *(const f16x8*)(wp + 8);
      float sum = 0.f;
#pragma unroll
      for (int q = 0; q < 8; ++q)
        sum += (float)h0[q]*(float)w0[q] + (float)h1[q]*(float)w1[q];
#pragma unroll
      for (int d = 1; d < 64; d <<= 1) sum += __shfl_xor(sum, d);
      if (lane == 0)
        lg[(size_t)(xg*32 + rowl)*256 + cg*8 + oc] = sum + bpp[cg*8 + oc];
    }
  }
  __syncthreads();   // drain lg stores
  if (tid == 0) {
    if (!xloc) __threadfence();
    __hip_atomic_store(flg + cg, 513u, __ATOMIC_RELAXED, __HIP_MEMORY_SCOPE_AGENT);
  }
  if (wv == 0) {
    u32 v = 513u;
    int guard = 0;
    for (;;) {
      if (lane < 32)
        v = __hip_atomic_load(flg + lane, __ATOMIC_RELAXED, __HIP_MEMORY_SCOPE_AGENT);
      if (__all(v >= 513u)) break;
      __builtin_amdgcn_s_sleep(1);
      if (++guard > (1 << 24)) break;
    }
    if (lane == 0) {
      if (xloc) { asm volatile("buffer_inv sc0" ::: "memory"); }
      else      { __threadfence(); }
    }
  }
  __syncthreads();
  // ---- softmax: this block handles row xg*32+cg, wave 0 only
  if (tid < 64) {
    int rowg = xg*32 + cg;
    const float* lr = lg + (size_t)rowg*256;
    float v0 = lr[tid], v1 = lr[tid+64], v2 = lr[tid+128], v3 = lr[tid+192];
    float mx = fmaxf(fmaxf(v0, v1), fmaxf(v2, v3));
#pragma unroll
    for (int d = 1; d < 64; d <<= 1) mx = fmaxf(mx, __shfl_xor(mx, d));
    float e0 = __expf(v0-mx), e1 = __expf(v1-mx), e2 = __expf(v2-mx), e3 = __expf(v3-mx);
    float sm = e0+e1+e2+e3;
#pragma unroll
    for (int d = 1; d < 64; d <<= 1) sm += __shfl_xor(sm, d);
    float inv = 1.0f / sm;
    float* orow = out + (size_t)rowg*256;
    orow[tid]      = e0*inv;
    orow[tid+64]   = e1*inv;
    orow[tid+128]  = e2*inv;
    orow[tid+192]  = e3*inv;
  }
}

extern "C" void kernel_launch(void* const* d_in, const int* in_sizes, int n_in,
                              void* d_out, int out_size, void* d_ws, size_t ws_size,
                              hipStream_t stream) {
  (void)in_sizes; (void)n_in; (void)out_size; (void)ws_size;
  const float* x   = (const float*)d_in[0];
  const float* Wgx = (const float*)d_in[1];
  const float* Wgh = (const float*)d_in[2];
  const float* bg  = (const float*)d_in[3];
  const float* Wix = (const float*)d_in[4];
  const float* Wih = (const float*)d_in[5];
  const float* bi  = (const float*)d_in[6];
  const float* Wfx = (const float*)d_in[7];
  const float* Wfh = (const float*)d_in[8];
  const float* bf  = (const float*)d_in[9];
  const float* Wox = (const float*)d_in[10];
  const float* Woh = (const float*)d_in[11];
  const float* bo  = (const float*)d_in[12];
  const float* Wph = (const float*)d_in[13];
  const float* bp  = (const float*)d_in[14];

  char* ws = (char*)d_ws;
  f16*   WT   = (f16*)(ws + WS_WT);
  f16*   WphT = (f16*)(ws + WS_WPHT);
  f16*   hbuf = (f16*)(ws + WS_HBUF);
  float* lg   = (float*)(ws + WS_LG);
  u32*   cnt  = (u32*)(ws + WS_CNT);
  u32*   xcd  = (u32*)(ws + WS_XCD);

  // h0 = 0 (buffer 0); flags + xcd table = 0 (replay-safe, stale-value-safe)
  hipMemsetAsync(hbuf, 0, 524288, stream);
  hipMemsetAsync(cnt, 0, 2048, stream);

  prep_wt<<<5120, 256, 0, stream>>>(Wgh, Wih, Wfh, Woh, Wgx, Wix, Wfx, Wox, WT);
  prep_wph<<<256, 256, 0, stream>>>(Wph, WphT);
  lstm_main<<<256, 512, 0, stream>>>(x, WT, WphT, hbuf,
                                     bg, bi, bf, bo, bp,
                                     lg, cnt, xcd, (float*)d_out);
}

// Round 4
// 9453.842 us; speedup vs baseline: 5.4752x; 1.2407x over previous
//
#include <hip/hip_runtime.h>

// LSTM fused kernel for MI355X (gfx950) — round 4: XCD-measured role assignment.
// Persistent kernel, 256 blocks (1/CU), weight-stationary fp16 MFMA.
// Each block reads HW_REG_XCC_ID and takes a ticket on its XCD's counter.
// If all 8 XCDs hold exactly 32 blocks: group xg = physical XCD (h exchange and
// barrier flags stay inside one coherent L2; acquire = L1-inv only, release =
// nothing beyond the barrier's vmcnt drain). Otherwise: fallback to bid-derived
// roles + per-step threadfence (slow but correct).
// Per step: z[32,128] per block = [h|x] @ W-slice (K=1280), col-split across 8
// waves (16 z-cols x full K, B weight-stationary in 160 regs/wave).
// Workspace (~12.4 MB):
//   WT   fp16 [4096][1280]  @ 0          WphT fp16 [256][1024] @ 10485760
//   hbuf fp16 [2][256][1024] @ 11010048  lg f32 [256][256] @ 12058624
//   cnt  u32 [8][32] @ 12320768          tick u32 [8] @ 12321792

typedef _Float16 f16;
typedef _Float16 f16x8 __attribute__((ext_vector_type(8)));
typedef _Float16 f16x4 __attribute__((ext_vector_type(4)));
typedef float f32x4 __attribute__((ext_vector_type(4)));
typedef unsigned int u32;

#define WS_WT    0
#define WS_WPHT  10485760
#define WS_HBUF  11010048
#define WS_LG    12058624
#define WS_CNT   12320768
#define WS_TICK  12321792

__device__ __forceinline__ float sigm(float v) { return 1.0f / (1.0f + __expf(-v)); }
__device__ __forceinline__ float tanhfast(float v) {
  float t = __expf(-2.0f * fabsf(v));
  float r = (1.0f - t) / (1.0f + t);
  return v < 0.0f ? -r : r;
}

// ---------- prep: WT[n][k], n=gate*1024+j (z-col), k<1024 -> Wh[k][j], else Wx[k-1024][j]
__global__ __launch_bounds__(256) void prep_wt(
    const float* __restrict__ Wgh, const float* __restrict__ Wih,
    const float* __restrict__ Wfh, const float* __restrict__ Woh,
    const float* __restrict__ Wgx, const float* __restrict__ Wix,
    const float* __restrict__ Wfx, const float* __restrict__ Wox,
    f16* __restrict__ WT)
{
  __shared__ float tile[32][33];
  int bid = blockIdx.x;
  int gate = bid / 1280;
  int rem  = bid % 1280;
  int jt = rem / 40, kt = rem % 40;
  const float* srcH = (gate==0)?Wgh:(gate==1)?Wih:(gate==2)?Wfh:Woh;
  const float* srcX = (gate==0)?Wgx:(gate==1)?Wix:(gate==2)?Wfx:Wox;
  const float* src = (kt < 32) ? (srcH + (size_t)(kt*32)*1024)
                               : (srcX + (size_t)(kt*32 - 1024)*1024);
  int t = threadIdx.x;
  {
    int jl = t & 31, kg = t >> 5;
#pragma unroll
    for (int it = 0; it < 4; ++it) {
      int kl = kg + it*8;
      tile[kl][jl] = src[(size_t)kl*1024 + jt*32 + jl];
    }
  }
  __syncthreads();
  {
    int kl = t & 31, jg = t >> 5;
#pragma unroll
    for (int it = 0; it < 4; ++it) {
      int jl2 = jg + it*8;
      WT[(size_t)(gate*1024 + jt*32 + jl2)*1280 + kt*32 + kl] = (f16)tile[kl][jl2];
    }
  }
}

// ---------- prep: WphT[oc][k] = W_ph[k][oc], fp16
__global__ __launch_bounds__(256) void prep_wph(const float* __restrict__ Wph,
                                                f16* __restrict__ WphT)
{
  __shared__ float tile[32][33];
  int bid = blockIdx.x;
  int jt = bid & 7, kt = bid >> 3;
  int t = threadIdx.x;
  {
    int jl = t & 31, kg = t >> 5;
#pragma unroll
    for (int it = 0; it < 4; ++it) {
      int kl = kg + it*8;
      tile[kl][jl] = Wph[(size_t)(kt*32 + kl)*256 + jt*32 + jl];
    }
  }
  __syncthreads();
  {
    int kl = t & 31, jg = t >> 5;
#pragma unroll
    for (int it = 0; it < 4; ++it) {
      int jl2 = jg + it*8;
      WphT[(size_t)(jt*32 + jl2)*1024 + kt*32 + kl] = (f16)tile[kl][jl2];
    }
  }
}

// ---------- main persistent LSTM kernel
// LDS: A-tile (swizzled) 0..81920, zbuf [4][32][32]f32 81920..98304,
//      c [32][32]f32 98304..102400, role-broadcast @102400 (ticket,xloc).
__global__ __launch_bounds__(512, 2) void lstm_main(
    const float* __restrict__ x, const f16* __restrict__ WT,
    const f16* __restrict__ WphT, f16* __restrict__ hbuf,
    const float* __restrict__ bgp, const float* __restrict__ bip,
    const float* __restrict__ bfp, const float* __restrict__ bop,
    const float* __restrict__ bpp, float* __restrict__ lg,
    u32* __restrict__ cnt, u32* __restrict__ tick, float* __restrict__ out)
{
  __shared__ __align__(16) char smem[102416];
  const int tid  = threadIdx.x;
  const int lane = tid & 63;
  const int wv   = tid >> 6;
  const int gate = wv >> 1;        // wave's gate (0..3)
  const int half = wv & 1;         // wave's 16-col half within gate
  const int l15 = lane & 15, l4 = lane >> 4;

  // ---- measure XCD, take ticket on per-XCD counter
  u32 myxcd;
  asm volatile("s_getreg_b32 %0, hwreg(HW_REG_XCC_ID)" : "=s"(myxcd));
  myxcd &= 7u;
  if (tid == 0) {
    u32 t = __hip_atomic_fetch_add(tick + myxcd, 1u,
                                   __ATOMIC_RELAXED, __HIP_MEMORY_SCOPE_AGENT);
    *(volatile u32*)(smem + 102400) = t;
  }
  // wave0: wait until all 256 blocks announced; check even 32/XCD split
  if (wv == 0) {
    u32 v = 0;
    int guard = 0;
    for (;;) {
      v = (lane < 8) ? __hip_atomic_load(tick + lane, __ATOMIC_RELAXED,
                                         __HIP_MEMORY_SCOPE_AGENT) : 0u;
      u32 sum = v;
      sum += __shfl_xor(sum, 1);
      sum += __shfl_xor(sum, 2);
      sum += __shfl_xor(sum, 4);
      if (__shfl(sum, 0) == 256u) break;
      __builtin_amdgcn_s_sleep(1);
      if (++guard > (1 << 24)) break;
    }
    int even = __all((lane < 8) ? (v == 32u) : 1);
    if (lane == 0) *(volatile u32*)(smem + 102404) = (u32)even;
  }
  __syncthreads();
  const bool xloc = (*(volatile u32*)(smem + 102404)) != 0u;
  const u32 myticket = *(volatile u32*)(smem + 102400);
  const int xg = xloc ? (int)myxcd   : (blockIdx.x & 7);   // batch-tile group
  const int cg = xloc ? (int)myticket : (blockIdx.x >> 3); // column slice 0..31
  u32* flg = cnt + xg*32;

  // ---- weight-stationary B fragments: 40 x f16x8 = 160 regs
  f16x8 Breg[40];
  {
    const int ncol = gate*1024 + cg*32 + half*16 + l15;   // global z-col
    const f16* wb = WT + (size_t)ncol*1280 + l4*8;
#pragma unroll 40
    for (int kk = 0; kk < 40; ++kk)
      Breg[kk] = *(const f16x8*)(wb + kk*32);
  }

  // per-thread bias (gate phase handles col = tid&31)
  const int bcol = cg*32 + (tid & 31);
  const float bgr = bgp[bcol], bir = bip[bcol], bfr = bfp[bcol], bor = bop[bcol];

  // A-frag addressing: addr = (row*2560 + l4*16 + kk*64) ^ ((row&7)<<4)
  u32 aoff0, aoff1, aswz;
  {
    aoff0 = (u32)l15*2560u + (u32)(l4*16);
    aoff1 = aoff0 + 16u*2560u;
    aswz  = ((u32)(l15 & 7)) << 4;
  }
  // staging indices
  const int srow = tid >> 4;
  const int sseg = tid & 15;
  const u32 swzr = ((u32)(srow & 7) << 4);
  const int grow = xg*32 + srow;

  // zero c
  *(float*)(smem + 98304 + tid*4) = 0.0f;
  *(float*)(smem + 98304 + (tid + 512)*4) = 0.0f;
  __syncthreads();

#pragma unroll 1
  for (int s = 0; s < 512; ++s) {
    // ---- group barrier: wait for all 32 blocks to have finished step s-1
    if (s > 0) {
      if (wv == 0) {
        const u32 tgt = (u32)s;
        u32 v = tgt;
        int guard = 0;
        for (;;) {
          if (lane < 32)
            v = __hip_atomic_load(flg + lane, __ATOMIC_RELAXED, __HIP_MEMORY_SCOPE_AGENT);
          if (__all(v >= tgt)) break;
          __builtin_amdgcn_s_sleep(1);
          if (++guard > (1 << 24)) break;
        }
        if (lane == 0) {
          if (xloc) {
            // producers share this XCD's L2; only vL1 can be stale
            asm volatile("buffer_inv sc0\n\ts_waitcnt vmcnt(0)" ::: "memory");
          } else {
            __threadfence();   // cross-XCD fallback: L2 wb+inv
          }
        }
      }
      __syncthreads();
    }
    // ---- stage A tile [32 rows x 1280] fp16, XOR-swizzled
    {
      const f16* hsrc = hbuf + (size_t)(s & 1)*262144 + (size_t)grow*1024;
#pragma unroll
      for (int j = 0; j < 8; ++j) {
        int chunk = sseg + 16*j;                       // 16B chunk of h row
        uint4 v = *(const uint4*)(hsrc + chunk*8);
        *(uint4*)(smem + ((srow*2560u + 16u*(u32)chunk) ^ swzr)) = v;
      }
      const float* xsrc = x + ((size_t)grow*512 + (size_t)s)*256;
#pragma unroll
      for (int j = 0; j < 4; ++j) {
        int chunk = sseg + 16*j;                       // float4 chunk of x row
        float4 v = *(const float4*)(xsrc + chunk*4);
        f16x4 hv;
        hv[0] = (f16)v.x; hv[1] = (f16)v.y; hv[2] = (f16)v.z; hv[3] = (f16)v.w;
        *(f16x4*)(smem + ((srow*2560u + 2048u + 8u*(u32)chunk) ^ swzr)) = hv;
      }
    }
    __syncthreads();
    // ---- K loop: full K=1280 per wave, 16 z-cols
    f32x4 acc0 = {}, acc1 = {};
#pragma unroll 40
    for (int kk = 0; kk < 40; ++kk) {
      f16x8 av0 = *(const f16x8*)(smem + ((aoff0 + (u32)kk*64u) ^ aswz));
      f16x8 av1 = *(const f16x8*)(smem + ((aoff1 + (u32)kk*64u) ^ aswz));
      acc0 = __builtin_amdgcn_mfma_f32_16x16x32_f16(av0, Breg[kk], acc0, 0, 0, 0);
      acc1 = __builtin_amdgcn_mfma_f32_16x16x32_f16(av1, Breg[kk], acc1, 0, 0, 0);
    }
    // write z to zbuf[gate][row][col] (wave-private region, no pre-sync needed)
    {
      const u32 zb = 81920u + (u32)(gate*1024 + half*16 + l15)*4u;
#pragma unroll
      for (int i = 0; i < 4; ++i) {
        u32 r0 = (u32)(l4*4 + i);
        *(float*)(smem + zb + r0*128u)         = acc0[i];
        *(float*)(smem + zb + (r0 + 16u)*128u) = acc1[i];
      }
    }
    __syncthreads();
    // ---- gates + c/h update (512 threads, rows tid>>5 and +16, col tid&31)
    {
      f16* hw = hbuf + (size_t)((s & 1) ^ 1)*262144;
      const int row = tid >> 5, col = tid & 31;
      const int gcol = cg*32 + col;
#pragma unroll
      for (int e2 = 0; e2 < 2; ++e2) {
        const int rr = row + e2*16;
        const u32 zo = (u32)(rr*128 + col*4);
        float zg = *(const float*)(smem + 81920u +        zo) + bgr;
        float zi = *(const float*)(smem + 81920u + 4096u + zo) + bir;
        float zf = *(const float*)(smem + 81920u + 8192u + zo) + bfr;
        float zv = *(const float*)(smem + 81920u + 12288u + zo) + bor;
        float* cp = (float*)(smem + 98304u + (u32)(rr*32 + col)*4u);
        float cv = *cp;
        float gv = tanhfast(zg);
        float iv = sigm(zi);
        float fv = sigm(zf);
        float ov = sigm(zv);
        float cn = gv*iv + cv*fv;
        *cp = cn;
        hw[(size_t)(xg*32 + rr)*1024 + gcol] = (f16)(tanhfast(cn) * ov);
      }
    }
    __syncthreads();   // drains all waves' vmcnt before flag release
    if (tid == 0) {
      if (!xloc) __threadfence();
      __hip_atomic_store(flg + cg, (u32)(s + 1),
                         __ATOMIC_RELAXED, __HIP_MEMORY_SCOPE_AGENT);
    }
  }

  // ---- epilogue: wait for whole group at step 512, then logits = h @ WphT + bp
  if (wv == 0) {
    u32 v = 512u;
    int guard = 0;
    for (;;) {
      if (lane < 32)
        v = __hip_atomic_load(flg + lane, __ATOMIC_RELAXED, __HIP_MEMORY_SCOPE_AGENT);
      if (__all(v >= 512u)) break;
      __builtin_amdgcn_s_sleep(1);
      if (++guard > (1 << 24)) break;
    }
    if (lane == 0) {
      if (xloc) { asm volatile("buffer_inv sc0\n\ts_waitcnt vmcnt(0)" ::: "memory"); }
      else      { __threadfence(); }
    }
  }
  __syncthreads();
  {
#pragma unroll 1
    for (int p = 0; p < 32; ++p) {
      int rowl = wv*4 + (p >> 3);
      int oc   = p & 7;
      const f16* hp = hbuf + (size_t)(xg*32 + rowl)*1024 + lane*16;  // buf 0 = h_T
      const f16* wp = WphT + (size_t)(cg*8 + oc)*1024 + lane*16;
      f16x8 h0 = *(const f16x8*)hp;
      f16x8 h1 = *(const f16x8*)(hp + 8);
      f16x8 w0 = *(const f16x8*)wp;
      f16x8 w1 = *(const f16x8*)(wp + 8);
      float sum = 0.f;
#pragma unroll
      for (int q = 0; q < 8; ++q)
        sum += (float)h0[q]*(float)w0[q] + (float)h1[q]*(float)w1[q];
#pragma unroll
      for (int d = 1; d < 64; d <<= 1) sum += __shfl_xor(sum, d);
      if (lane == 0)
        lg[(size_t)(xg*32 + rowl)*256 + cg*8 + oc] = sum + bpp[cg*8 + oc];
    }
  }
  __syncthreads();   // drain lg stores
  if (tid == 0) {
    if (!xloc) __threadfence();
    __hip_atomic_store(flg + cg, 513u, __ATOMIC_RELAXED, __HIP_MEMORY_SCOPE_AGENT);
  }
  if (wv == 0) {
    u32 v = 513u;
    int guard = 0;
    for (;;) {
      if (lane < 32)
        v = __hip_atomic_load(flg + lane, __ATOMIC_RELAXED, __HIP_MEMORY_SCOPE_AGENT);
      if (__all(v >= 513u)) break;
      __builtin_amdgcn_s_sleep(1);
      if (++guard > (1 << 24)) break;
    }
    if (lane == 0) {
      if (xloc) { asm volatile("buffer_inv sc0\n\ts_waitcnt vmcnt(0)" ::: "memory"); }
      else      { __threadfence(); }
    }
  }
  __syncthreads();
  // ---- softmax: this block handles row xg*32+cg, wave 0 only
  if (tid < 64) {
    int rowg = xg*32 + cg;
    const float* lr = lg + (size_t)rowg*256;
    float v0 = lr[tid], v1 = lr[tid+64], v2 = lr[tid+128], v3 = lr[tid+192];
    float mx = fmaxf(fmaxf(v0, v1), fmaxf(v2, v3));
#pragma unroll
    for (int d = 1; d < 64; d <<= 1) mx = fmaxf(mx, __shfl_xor(mx, d));
    float e0 = __expf(v0-mx), e1 = __expf(v1-mx), e2 = __expf(v2-mx), e3 = __expf(v3-mx);
    float sm = e0+e1+e2+e3;
#pragma unroll
    for (int d = 1; d < 64; d <<= 1) sm += __shfl_xor(sm, d);
    float inv = 1.0f / sm;
    float* orow = out + (size_t)rowg*256;
    orow[tid]      = e0*inv;
    orow[tid+64]   = e1*inv;
    orow[tid+128]  = e2*inv;
    orow[tid+192]  = e3*inv;
  }
}

extern "C" void kernel_launch(void* const* d_in, const int* in_sizes, int n_in,
                              void* d_out, int out_size, void* d_ws, size_t ws_size,
                              hipStream_t stream) {
  (void)in_sizes; (void)n_in; (void)out_size; (void)ws_size;
  const float* x   = (const float*)d_in[0];
  const float* Wgx = (const float*)d_in[1];
  const float* Wgh = (const float*)d_in[2];
  const float* bg  = (const float*)d_in[3];
  const float* Wix = (const float*)d_in[4];
  const float* Wih = (const float*)d_in[5];
  const float* bi  = (const float*)d_in[6];
  const float* Wfx = (const float*)d_in[7];
  const float* Wfh = (const float*)d_in[8];
  const float* bf  = (const float*)d_in[9];
  const float* Wox = (const float*)d_in[10];
  const float* Woh = (const float*)d_in[11];
  const float* bo  = (const float*)d_in[12];
  const float* Wph = (const float*)d_in[13];
  const float* bp  = (const float*)d_in[14];

  char* ws = (char*)d_ws;
  f16*   WT   = (f16*)(ws + WS_WT);
  f16*   WphT = (f16*)(ws + WS_WPHT);
  f16*   hbuf = (f16*)(ws + WS_HBUF);
  float* lg   = (float*)(ws + WS_LG);
  u32*   cnt  = (u32*)(ws + WS_CNT);
  u32*   tick = (u32*)(ws + WS_TICK);

  // h0 = 0 (buffer 0); flags + tickets = 0 (replay-safe)
  hipMemsetAsync(hbuf, 0, 524288, stream);
  hipMemsetAsync(cnt, 0, 2048, stream);

  prep_wt<<<5120, 256, 0, stream>>>(Wgh, Wih, Wfh, Woh, Wgx, Wix, Wfx, Wox, WT);
  prep_wph<<<256, 256, 0, stream>>>(Wph, WphT);
  lstm_main<<<256, 512, 0, stream>>>(x, WT, WphT, hbuf,
                                     bg, bi, bf, bo, bp,
                                     lg, cnt, tick, (float*)d_out);
}

// Round 6
// 7841.782 us; speedup vs baseline: 6.6008x; 1.2056x over previous
//
#include <hip/hip_runtime.h>

// LSTM fused kernel for MI355X (gfx950) — round 6: round-4 sync (proven) +
// forced weight residency (opacify) + launch_bounds(512,1) + x prefetch.
// Persistent kernel, 256 blocks (1/CU), weight-stationary fp16 MFMA.
// Roles derived from measured XCD (ticket on per-XCD counter); xloc path:
// acquire = buffer_inv sc0 (L1 only), flags = relaxed agent atomics.
// Per step: z[32,128] = [h|x] @ W-slice (K=1280), col-split across 8 waves
// (16 z-cols x full K, B stationary in 160 VGPRs pinned via asm opacify).
// Workspace (~12.4 MB):
//   WT   fp16 [4096][1280]  @ 0          WphT fp16 [256][1024] @ 10485760
//   hbuf fp16 [2][256][1024] @ 11010048  lg f32 [256][256] @ 12058624
//   cnt  u32 [8][32] @ 12320768          tick u32 [8] @ 12321792

typedef _Float16 f16;
typedef _Float16 f16x8 __attribute__((ext_vector_type(8)));
typedef _Float16 f16x4 __attribute__((ext_vector_type(4)));
typedef float f32x4 __attribute__((ext_vector_type(4)));
typedef unsigned int u32;

#define WS_WT    0
#define WS_WPHT  10485760
#define WS_HBUF  11010048
#define WS_LG    12058624
#define WS_CNT   12320768
#define WS_TICK  12321792

__device__ __forceinline__ float sigm(float v) { return 1.0f / (1.0f + __expf(-v)); }
__device__ __forceinline__ float tanhfast(float v) {
  float t = __expf(-2.0f * fabsf(v));
  float r = (1.0f - t) / (1.0f + t);
  return v < 0.0f ? -r : r;
}

// ---------- prep: WT[n][k], n=gate*1024+j (z-col), k<1024 -> Wh[k][j], else Wx[k-1024][j]
__global__ __launch_bounds__(256) void prep_wt(
    const float* __restrict__ Wgh, const float* __restrict__ Wih,
    const float* __restrict__ Wfh, const float* __restrict__ Woh,
    const float* __restrict__ Wgx, const float* __restrict__ Wix,
    const float* __restrict__ Wfx, const float* __restrict__ Wox,
    f16* __restrict__ WT)
{
  __shared__ float tile[32][33];
  int bid = blockIdx.x;
  int gate = bid / 1280;
  int rem  = bid % 1280;
  int jt = rem / 40, kt = rem % 40;
  const float* srcH = (gate==0)?Wgh:(gate==1)?Wih:(gate==2)?Wfh:Woh;
  const float* srcX = (gate==0)?Wgx:(gate==1)?Wix:(gate==2)?Wfx:Wox;
  const float* src = (kt < 32) ? (srcH + (size_t)(kt*32)*1024)
                               : (srcX + (size_t)(kt*32 - 1024)*1024);
  int t = threadIdx.x;
  {
    int jl = t & 31, kg = t >> 5;
#pragma unroll
    for (int it = 0; it < 4; ++it) {
      int kl = kg + it*8;
      tile[kl][jl] = src[(size_t)kl*1024 + jt*32 + jl];
    }
  }
  __syncthreads();
  {
    int kl = t & 31, jg = t >> 5;
#pragma unroll
    for (int it = 0; it < 4; ++it) {
      int jl2 = jg + it*8;
      WT[(size_t)(gate*1024 + jt*32 + jl2)*1280 + kt*32 + kl] = (f16)tile[kl][jl2];
    }
  }
}

// ---------- prep: WphT[oc][k] = W_ph[k][oc], fp16
__global__ __launch_bounds__(256) void prep_wph(const float* __restrict__ Wph,
                                                f16* __restrict__ WphT)
{
  __shared__ float tile[32][33];
  int bid = blockIdx.x;
  int jt = bid & 7, kt = bid >> 3;
  int t = threadIdx.x;
  {
    int jl = t & 31, kg = t >> 5;
#pragma unroll
    for (int it = 0; it < 4; ++it) {
      int kl = kg + it*8;
      tile[kl][jl] = Wph[(size_t)(kt*32 + kl)*256 + jt*32 + jl];
    }
  }
  __syncthreads();
  {
    int kl = t & 31, jg = t >> 5;
#pragma unroll
    for (int it = 0; it < 4; ++it) {
      int jl2 = jg + it*8;
      WphT[(size_t)(jt*32 + jl2)*1024 + kt*32 + kl] = (f16)tile[kl][jl2];
    }
  }
}

// ---------- main persistent LSTM kernel
// LDS: A-tile (swizzled) 0..81920, zbuf [4][32][32]f32 81920..98304,
//      c [32][32]f32 98304..102400, role-broadcast @102400 (ticket,xloc).
__global__ __launch_bounds__(512, 1) void lstm_main(
    const float* __restrict__ x, const f16* __restrict__ WT,
    const f16* __restrict__ WphT, f16* __restrict__ hbuf,
    const float* __restrict__ bgp, const float* __restrict__ bip,
    const float* __restrict__ bfp, const float* __restrict__ bop,
    const float* __restrict__ bpp, float* __restrict__ lg,
    u32* __restrict__ cnt, u32* __restrict__ tick, float* __restrict__ out)
{
  __shared__ __align__(16) char smem[102416];
  const int tid  = threadIdx.x;
  const int lane = tid & 63;
  const int wv   = tid >> 6;
  const int gate = wv >> 1;        // wave's gate (0..3)
  const int half = wv & 1;         // wave's 16-col half within gate
  const int l15 = lane & 15, l4 = lane >> 4;

  // ---- measure XCD, take ticket on per-XCD counter
  u32 myxcd;
  asm volatile("s_getreg_b32 %0, hwreg(HW_REG_XCC_ID)" : "=s"(myxcd));
  myxcd &= 7u;
  if (tid == 0) {
    u32 t = __hip_atomic_fetch_add(tick + myxcd, 1u,
                                   __ATOMIC_RELAXED, __HIP_MEMORY_SCOPE_AGENT);
    *(volatile u32*)(smem + 102400) = t;
  }
  // wave0: wait until all 256 blocks announced; check even 32/XCD split
  if (wv == 0) {
    u32 v = 0;
    int guard = 0;
    for (;;) {
      v = (lane < 8) ? __hip_atomic_load(tick + lane, __ATOMIC_RELAXED,
                                         __HIP_MEMORY_SCOPE_AGENT) : 0u;
      u32 sum = v;
      sum += __shfl_xor(sum, 1);
      sum += __shfl_xor(sum, 2);
      sum += __shfl_xor(sum, 4);
      if (__shfl(sum, 0) == 256u) break;
      __builtin_amdgcn_s_sleep(1);
      if (++guard > (1 << 24)) break;
    }
    int even = __all((lane < 8) ? (v == 32u) : 1);
    if (lane == 0) *(volatile u32*)(smem + 102404) = (u32)even;
  }
  __syncthreads();
  const bool xloc = (*(volatile u32*)(smem + 102404)) != 0u;
  const u32 myticket = *(volatile u32*)(smem + 102400);
  const int xg = xloc ? (int)myxcd    : (blockIdx.x & 7);   // batch-tile group
  const int cg = xloc ? (int)myticket : (blockIdx.x >> 3);  // column slice 0..31
  u32* flg = cnt + xg*32;

  // ---- weight-stationary B fragments: 40 x f16x8 = 160 VGPR, pinned via asm
  f16x8 Breg[40];
  {
    const int ncol = gate*1024 + cg*32 + half*16 + l15;   // global z-col
    const f16* wb = WT + (size_t)ncol*1280 + l4*8;
#pragma unroll
    for (int kk = 0; kk < 40; ++kk) {
      Breg[kk] = *(const f16x8*)(wb + kk*32);
      asm volatile("" : "+v"(Breg[kk]));   // opaque: no remat, must stay live
    }
  }

  // per-thread bias (gate phase handles col = tid&31)
  const int bcol = cg*32 + (tid & 31);
  const float bgr = bgp[bcol], bir = bip[bcol], bfr = bfp[bcol], bor = bop[bcol];

  // A-frag addressing: addr = (row*2560 + l4*16 + kk*64) ^ ((row&7)<<4)
  u32 aoff0, aoff1, aswz;
  {
    aoff0 = (u32)l15*2560u + (u32)(l4*16);
    aoff1 = aoff0 + 16u*2560u;
    aswz  = ((u32)(l15 & 7)) << 4;
  }
  // staging indices
  const int srow = tid >> 4;
  const int sseg = tid & 15;
  const u32 swzr = ((u32)(srow & 7) << 4);
  const int grow = xg*32 + srow;

  // zero c
  *(float*)(smem + 98304 + tid*4) = 0.0f;
  *(float*)(smem + 98304 + (tid + 512)*4) = 0.0f;
  __syncthreads();

#pragma unroll 1
  for (int s = 0; s < 512; ++s) {
    // ---- x prefetch: independent of h, issued before the barrier wait
    float4 xv0, xv1, xv2, xv3;
    {
      const float* xsrc = x + ((size_t)grow*512 + (size_t)s)*256;
      xv0 = *(const float4*)(xsrc + (sseg     )*4);
      xv1 = *(const float4*)(xsrc + (sseg + 16)*4);
      xv2 = *(const float4*)(xsrc + (sseg + 32)*4);
      xv3 = *(const float4*)(xsrc + (sseg + 48)*4);
    }
    // ---- group barrier: wait for all 32 blocks to have finished step s-1
    if (s > 0) {
      if (wv == 0) {
        const u32 tgt = (u32)s;
        u32 v = tgt;
        int guard = 0;
        for (;;) {
          if (lane < 32)
            v = __hip_atomic_load(flg + lane, __ATOMIC_RELAXED, __HIP_MEMORY_SCOPE_AGENT);
          if (__all(v >= tgt)) break;
          __builtin_amdgcn_s_sleep(1);
          if (++guard > (1 << 24)) break;
        }
        if (lane == 0) {
          if (xloc) {
            // producers share this XCD's L2; only vL1 can be stale
            asm volatile("buffer_inv sc0\n\ts_waitcnt vmcnt(0)" ::: "memory");
          } else {
            __threadfence();   // cross-XCD fallback: L2 wb+inv
          }
        }
      }
      __syncthreads();
    }
    // ---- stage A tile [32 rows x 1280] fp16, XOR-swizzled
    {
      const f16* hsrc = hbuf + (size_t)(s & 1)*262144 + (size_t)grow*1024;
#pragma unroll
      for (int j = 0; j < 8; ++j) {
        int chunk = sseg + 16*j;                       // 16B chunk of h row
        uint4 v = *(const uint4*)(hsrc + chunk*8);
        *(uint4*)(smem + ((srow*2560u + 16u*(u32)chunk) ^ swzr)) = v;
      }
      f16x4 hv;
      hv[0] = (f16)xv0.x; hv[1] = (f16)xv0.y; hv[2] = (f16)xv0.z; hv[3] = (f16)xv0.w;
      *(f16x4*)(smem + ((srow*2560u + 2048u + 8u*(u32)(sseg     )) ^ swzr)) = hv;
      hv[0] = (f16)xv1.x; hv[1] = (f16)xv1.y; hv[2] = (f16)xv1.z; hv[3] = (f16)xv1.w;
      *(f16x4*)(smem + ((srow*2560u + 2048u + 8u*(u32)(sseg + 16)) ^ swzr)) = hv;
      hv[0] = (f16)xv2.x; hv[1] = (f16)xv2.y; hv[2] = (f16)xv2.z; hv[3] = (f16)xv2.w;
      *(f16x4*)(smem + ((srow*2560u + 2048u + 8u*(u32)(sseg + 32)) ^ swzr)) = hv;
      hv[0] = (f16)xv3.x; hv[1] = (f16)xv3.y; hv[2] = (f16)xv3.z; hv[3] = (f16)xv3.w;
      *(f16x4*)(smem + ((srow*2560u + 2048u + 8u*(u32)(sseg + 48)) ^ swzr)) = hv;
    }
    __syncthreads();
    // ---- K loop: full K=1280 per wave, 16 z-cols
    f32x4 acc0 = {}, acc1 = {};
#pragma unroll
    for (int kk = 0; kk < 40; ++kk) {
      f16x8 av0 = *(const f16x8*)(smem + ((aoff0 + (u32)kk*64u) ^ aswz));
      f16x8 av1 = *(const f16x8*)(smem + ((aoff1 + (u32)kk*64u) ^ aswz));
      acc0 = __builtin_amdgcn_mfma_f32_16x16x32_f16(av0, Breg[kk], acc0, 0, 0, 0);
      acc1 = __builtin_amdgcn_mfma_f32_16x16x32_f16(av1, Breg[kk], acc1, 0, 0, 0);
    }
    // write z to zbuf[gate][row][col] (wave-private region)
    {
      const u32 zb = 81920u + (u32)(gate*1024 + half*16 + l15)*4u;
#pragma unroll
      for (int i = 0; i < 4; ++i) {
        u32 r0 = (u32)(l4*4 + i);
        *(float*)(smem + zb + r0*128u)         = acc0[i];
        *(float*)(smem + zb + (r0 + 16u)*128u) = acc1[i];
      }
    }
    __syncthreads();
    // ---- gates + c/h update (512 threads, rows tid>>5 and +16, col tid&31)
    {
      f16* hw = hbuf + (size_t)((s & 1) ^ 1)*262144;
      const int row = tid >> 5, col = tid & 31;
      const int gcol = cg*32 + col;
#pragma unroll
      for (int e2 = 0; e2 < 2; ++e2) {
        const int rr = row + e2*16;
        const u32 zo = (u32)(rr*128 + col*4);
        float zg = *(const float*)(smem + 81920u +          zo) + bgr;
        float zi = *(const float*)(smem + 81920u + 4096u  + zo) + bir;
        float zf = *(const float*)(smem + 81920u + 8192u  + zo) + bfr;
        float zv = *(const float*)(smem + 81920u + 12288u + zo) + bor;
        float* cp = (float*)(smem + 98304u + (u32)(rr*32 + col)*4u);
        float cv = *cp;
        float gv = tanhfast(zg);
        float iv = sigm(zi);
        float fv = sigm(zf);
        float ov = sigm(zv);
        float cn = gv*iv + cv*fv;
        *cp = cn;
        hw[(size_t)(xg*32 + rr)*1024 + gcol] = (f16)(tanhfast(cn) * ov);
      }
    }
    __syncthreads();   // drains all waves' stores (vmcnt) before flag release
    if (tid == 0) {
      if (!xloc) __threadfence();
      __hip_atomic_store(flg + cg, (u32)(s + 1),
                         __ATOMIC_RELAXED, __HIP_MEMORY_SCOPE_AGENT);
    }
  }

  // ---- epilogue: wait for whole group at step 512, then logits = h @ WphT + bp
  if (wv == 0) {
    u32 v = 512u;
    int guard = 0;
    for (;;) {
      if (lane < 32)
        v = __hip_atomic_load(flg + lane, __ATOMIC_RELAXED, __HIP_MEMORY_SCOPE_AGENT);
      if (__all(v >= 512u)) break;
      __builtin_amdgcn_s_sleep(1);
      if (++guard > (1 << 24)) break;
    }
    if (lane == 0) {
      if (xloc) { asm volatile("buffer_inv sc0\n\ts_waitcnt vmcnt(0)" ::: "memory"); }
      else      { __threadfence(); }
    }
  }
  __syncthreads();
  {
#pragma unroll 1
    for (int p = 0; p < 32; ++p) {
      int rowl = wv*4 + (p >> 3);
      int oc   = p & 7;
      const f16* hp = hbuf + (size_t)(xg*32 + rowl)*1024 + lane*16;  // buf 0 = h_T
      const f16* wp = WphT + (size_t)(cg*8 + oc)*1024 + lane*16;
      f16x8 h0 = *(const f16x8*)hp;
      f16x8 h1 = *(const f16x8*)(hp + 8);
      f16x8 w0 = *(const f16x8*)wp;
      f16x8 w1 = *(const f16x8*)(wp + 8);
      float sum = 0.f;
#pragma unroll
      for (int q = 0; q < 8; ++q)
        sum += (float)h0[q]*(float)w0[q] + (float)h1[q]*(float)w1[q];
#pragma unroll
      for (int d = 1; d < 64; d <<= 1) sum += __shfl_xor(sum, d);
      if (lane == 0)
        lg[(size_t)(xg*32 + rowl)*256 + cg*8 + oc] = sum + bpp[cg*8 + oc];
    }
  }
  __syncthreads();   // drain lg stores
  if (tid == 0) {
    if (!xloc) __threadfence();
    __hip_atomic_store(flg + cg, 513u, __ATOMIC_RELAXED, __HIP_MEMORY_SCOPE_AGENT);
  }
  if (wv == 0) {
    u32 v = 513u;
    int guard = 0;
    for (;;) {
      if (lane < 32)
        v = __hip_atomic_load(flg + lane, __ATOMIC_RELAXED, __HIP_MEMORY_SCOPE_AGENT);
      if (__all(v >= 513u)) break;
      __builtin_amdgcn_s_sleep(1);
      if (++guard > (1 << 24)) break;
    }
    if (lane == 0) {
      if (xloc) { asm volatile("buffer_inv sc0\n\ts_waitcnt vmcnt(0)" ::: "memory"); }
      else      { __threadfence(); }
    }
  }
  __syncthreads();
  // ---- softmax: this block handles row xg*32+cg, wave 0 only
  if (tid < 64) {
    int rowg = xg*32 + cg;
    const float* lr = lg + (size_t)rowg*256;
    float v0 = lr[tid], v1 = lr[tid+64], v2 = lr[tid+128], v3 = lr[tid+192];
    float mx = fmaxf(fmaxf(v0, v1), fmaxf(v2, v3));
#pragma unroll
    for (int d = 1; d < 64; d <<= 1) mx = fmaxf(mx, __shfl_xor(mx, d));
    float e0 = __expf(v0-mx), e1 = __expf(v1-mx), e2 = __expf(v2-mx), e3 = __expf(v3-mx);
    float sm = e0+e1+e2+e3;
#pragma unroll
    for (int d = 1; d < 64; d <<= 1) sm += __shfl_xor(sm, d);
    float inv = 1.0f / sm;
    float* orow = out + (size_t)rowg*256;
    orow[tid]      = e0*inv;
    orow[tid+64]   = e1*inv;
    orow[tid+128]  = e2*inv;
    orow[tid+192]  = e3*inv;
  }
}

extern "C" void kernel_launch(void* const* d_in, const int* in_sizes, int n_in,
                              void* d_out, int out_size, void* d_ws, size_t ws_size,
                              hipStream_t stream) {
  (void)in_sizes; (void)n_in; (void)out_size; (void)ws_size;
  const float* x   = (const float*)d_in[0];
  const float* Wgx = (const float*)d_in[1];
  const float* Wgh = (const float*)d_in[2];
  const float* bg  = (const float*)d_in[3];
  const float* Wix = (const float*)d_in[4];
  const float* Wih = (const float*)d_in[5];
  const float* bi  = (const float*)d_in[6];
  const float* Wfx = (const float*)d_in[7];
  const float* Wfh = (const float*)d_in[8];
  const float* bf  = (const float*)d_in[9];
  const float* Wox = (const float*)d_in[10];
  const float* Woh = (const float*)d_in[11];
  const float* bo  = (const float*)d_in[12];
  const float* Wph = (const float*)d_in[13];
  const float* bp  = (const float*)d_in[14];

  char* ws = (char*)d_ws;
  f16*   WT   = (f16*)(ws + WS_WT);
  f16*   WphT = (f16*)(ws + WS_WPHT);
  f16*   hbuf = (f16*)(ws + WS_HBUF);
  float* lg   = (float*)(ws + WS_LG);
  u32*   cnt  = (u32*)(ws + WS_CNT);
  u32*   tick = (u32*)(ws + WS_TICK);

  // h0 = 0 (buffer 0); flags + tickets = 0 (replay-safe)
  hipMemsetAsync(hbuf, 0, 524288, stream);
  hipMemsetAsync(cnt, 0, 2048, stream);

  prep_wt<<<5120, 256, 0, stream>>>(Wgh, Wih, Wfh, Woh, Wgx, Wix, Wfx, Wox, WT);
  prep_wph<<<256, 256, 0, stream>>>(Wph, WphT);
  lstm_main<<<256, 512, 0, stream>>>(x, WT, WphT, hbuf,
                                     bg, bi, bf, bo, bp,
                                     lg, cnt, tick, (float*)d_out);
}

// Round 7
// 4798.237 us; speedup vs baseline: 10.7877x; 1.6343x over previous
//
#include <hip/hip_runtime.h>

// LSTM fused kernel for MI355X (gfx950) — round 7: 4-wave blocks (1 wave/SIMD,
// 512-VGPR budget) so the weight-stationary array ACTUALLY fits in registers.
// 256 blocks x 256 threads. Wave w = gate w: 32 z-cols x full K=1280,
// Breg[40][2] = 320 VGPRs + ~80 working < 512 budget -> no spill.
// Sync skeleton identical to round 4/6 (proven): XCD-measured roles, xloc path
// = relaxed agent flags + buffer_inv sc0 acquire; fallback = threadfence.
// Workspace (~12.4 MB):
//   WT   fp16 [4096][1280]  @ 0          WphT fp16 [256][1024] @ 10485760
//   hbuf fp16 [2][256][1024] @ 11010048  lg f32 [256][256] @ 12058624
//   cnt  u32 [8][32] @ 12320768          tick u32 [8] @ 12321792

typedef _Float16 f16;
typedef _Float16 f16x8 __attribute__((ext_vector_type(8)));
typedef _Float16 f16x4 __attribute__((ext_vector_type(4)));
typedef float f32x4 __attribute__((ext_vector_type(4)));
typedef unsigned int u32;

#define WS_WT    0
#define WS_WPHT  10485760
#define WS_HBUF  11010048
#define WS_LG    12058624
#define WS_CNT   12320768
#define WS_TICK  12321792

__device__ __forceinline__ float sigm(float v) { return 1.0f / (1.0f + __expf(-v)); }
__device__ __forceinline__ float tanhfast(float v) {
  float t = __expf(-2.0f * fabsf(v));
  float r = (1.0f - t) / (1.0f + t);
  return v < 0.0f ? -r : r;
}

// ---------- prep: WT[n][k], n=gate*1024+j (z-col), k<1024 -> Wh[k][j], else Wx[k-1024][j]
__global__ __launch_bounds__(256) void prep_wt(
    const float* __restrict__ Wgh, const float* __restrict__ Wih,
    const float* __restrict__ Wfh, const float* __restrict__ Woh,
    const float* __restrict__ Wgx, const float* __restrict__ Wix,
    const float* __restrict__ Wfx, const float* __restrict__ Wox,
    f16* __restrict__ WT)
{
  __shared__ float tile[32][33];
  int bid = blockIdx.x;
  int gate = bid / 1280;
  int rem  = bid % 1280;
  int jt = rem / 40, kt = rem % 40;
  const float* srcH = (gate==0)?Wgh:(gate==1)?Wih:(gate==2)?Wfh:Woh;
  const float* srcX = (gate==0)?Wgx:(gate==1)?Wix:(gate==2)?Wfx:Wox;
  const float* src = (kt < 32) ? (srcH + (size_t)(kt*32)*1024)
                               : (srcX + (size_t)(kt*32 - 1024)*1024);
  int t = threadIdx.x;
  {
    int jl = t & 31, kg = t >> 5;
#pragma unroll
    for (int it = 0; it < 4; ++it) {
      int kl = kg + it*8;
      tile[kl][jl] = src[(size_t)kl*1024 + jt*32 + jl];
    }
  }
  __syncthreads();
  {
    int kl = t & 31, jg = t >> 5;
#pragma unroll
    for (int it = 0; it < 4; ++it) {
      int jl2 = jg + it*8;
      WT[(size_t)(gate*1024 + jt*32 + jl2)*1280 + kt*32 + kl] = (f16)tile[kl][jl2];
    }
  }
}

// ---------- prep: WphT[oc][k] = W_ph[k][oc], fp16
__global__ __launch_bounds__(256) void prep_wph(const float* __restrict__ Wph,
                                                f16* __restrict__ WphT)
{
  __shared__ float tile[32][33];
  int bid = blockIdx.x;
  int jt = bid & 7, kt = bid >> 3;
  int t = threadIdx.x;
  {
    int jl = t & 31, kg = t >> 5;
#pragma unroll
    for (int it = 0; it < 4; ++it) {
      int kl = kg + it*8;
      tile[kl][jl] = Wph[(size_t)(kt*32 + kl)*256 + jt*32 + jl];
    }
  }
  __syncthreads();
  {
    int kl = t & 31, jg = t >> 5;
#pragma unroll
    for (int it = 0; it < 4; ++it) {
      int jl2 = jg + it*8;
      WphT[(size_t)(jt*32 + jl2)*1024 + kt*32 + kl] = (f16)tile[kl][jl2];
    }
  }
}

// ---------- main persistent LSTM kernel
// LDS: A-tile (swizzled) 0..81920, zbuf [4][32][32]f32 81920..98304,
//      c [32][32]f32 98304..102400, role-broadcast @102400 (ticket,xloc).
__global__ __launch_bounds__(256, 1) void lstm_main(
    const float* __restrict__ x, const f16* __restrict__ WT,
    const f16* __restrict__ WphT, f16* __restrict__ hbuf,
    const float* __restrict__ bgp, const float* __restrict__ bip,
    const float* __restrict__ bfp, const float* __restrict__ bop,
    const float* __restrict__ bpp, float* __restrict__ lg,
    u32* __restrict__ cnt, u32* __restrict__ tick, float* __restrict__ out)
{
  __shared__ __align__(16) char smem[102416];
  const int tid  = threadIdx.x;
  const int lane = tid & 63;
  const int wv   = tid >> 6;       // wave = gate (0..3)
  const int l15 = lane & 15, l4 = lane >> 4;

  // ---- measure XCD, take ticket on per-XCD counter
  u32 myxcd;
  asm volatile("s_getreg_b32 %0, hwreg(HW_REG_XCC_ID)" : "=s"(myxcd));
  myxcd &= 7u;
  if (tid == 0) {
    u32 t = __hip_atomic_fetch_add(tick + myxcd, 1u,
                                   __ATOMIC_RELAXED, __HIP_MEMORY_SCOPE_AGENT);
    *(volatile u32*)(smem + 102400) = t;
  }
  // wave0: wait until all 256 blocks announced; check even 32/XCD split
  if (wv == 0) {
    u32 v = 0;
    int guard = 0;
    for (;;) {
      v = (lane < 8) ? __hip_atomic_load(tick + lane, __ATOMIC_RELAXED,
                                         __HIP_MEMORY_SCOPE_AGENT) : 0u;
      u32 sum = v;
      sum += __shfl_xor(sum, 1);
      sum += __shfl_xor(sum, 2);
      sum += __shfl_xor(sum, 4);
      if (__shfl(sum, 0) == 256u) break;
      __builtin_amdgcn_s_sleep(1);
      if (++guard > (1 << 24)) break;
    }
    int even = __all((lane < 8) ? (v == 32u) : 1);
    if (lane == 0) *(volatile u32*)(smem + 102404) = (u32)even;
  }
  __syncthreads();
  const bool xloc = (*(volatile u32*)(smem + 102404)) != 0u;
  const u32 myticket = *(volatile u32*)(smem + 102400);
  const int xg = xloc ? (int)myxcd    : (blockIdx.x & 7);   // batch-tile group
  const int cg = xloc ? (int)myticket : (blockIdx.x >> 3);  // column slice 0..31
  u32* flg = cnt + xg*32;

  // ---- weight-stationary B fragments: 40 kk x 2 col-frags = 320 VGPR, pinned
  f16x8 Breg[40][2];
  {
    const f16* wb0 = WT + (size_t)(wv*1024 + cg*32      + l15)*1280 + l4*8;
    const f16* wb1 = WT + (size_t)(wv*1024 + cg*32 + 16 + l15)*1280 + l4*8;
#pragma unroll
    for (int kk = 0; kk < 40; ++kk) {
      Breg[kk][0] = *(const f16x8*)(wb0 + kk*32);
      asm volatile("" : "+v"(Breg[kk][0]));   // opaque: no remat, stays live
      Breg[kk][1] = *(const f16x8*)(wb1 + kk*32);
      asm volatile("" : "+v"(Breg[kk][1]));
    }
  }

  // per-thread bias (gate phase handles col = tid&31)
  const int bcol = cg*32 + (tid & 31);
  const float bgr = bgp[bcol], bir = bip[bcol], bfr = bfp[bcol], bor = bop[bcol];

  // A-frag addressing: addr = (row*2560 + l4*16 + kk*64) ^ ((row&7)<<4)
  u32 aoff0, aoff1, aswz;
  {
    aoff0 = (u32)l15*2560u + (u32)(l4*16);
    aoff1 = aoff0 + 16u*2560u;
    aswz  = ((u32)(l15 & 7)) << 4;
  }
  // staging indices: 32 rows x 8 segs (256 threads)
  const int srow = tid >> 3;
  const int sseg = tid & 7;
  const u32 swzr = ((u32)(srow & 7) << 4);
  const int grow = xg*32 + srow;

  // zero c (1024 f32 / 256 threads = 4 each)
#pragma unroll
  for (int e = 0; e < 4; ++e)
    *(float*)(smem + 98304 + (tid + e*256)*4) = 0.0f;
  __syncthreads();

#pragma unroll 1
  for (int s = 0; s < 512; ++s) {
    // ---- x prefetch (first 4 of 8 float4/thread): independent of h
    float4 xv0, xv1, xv2, xv3;
    {
      const float* xsrc = x + ((size_t)grow*512 + (size_t)s)*256;
      xv0 = *(const float4*)(xsrc + (sseg     )*4);
      xv1 = *(const float4*)(xsrc + (sseg +  8)*4);
      xv2 = *(const float4*)(xsrc + (sseg + 16)*4);
      xv3 = *(const float4*)(xsrc + (sseg + 24)*4);
    }
    // ---- group barrier: wait for all 32 blocks to have finished step s-1
    if (s > 0) {
      if (wv == 0) {
        const u32 tgt = (u32)s;
        u32 v = tgt;
        int guard = 0;
        for (;;) {
          if (lane < 32)
            v = __hip_atomic_load(flg + lane, __ATOMIC_RELAXED, __HIP_MEMORY_SCOPE_AGENT);
          if (__all(v >= tgt)) break;
          __builtin_amdgcn_s_sleep(1);
          if (++guard > (1 << 24)) break;
        }
        if (lane == 0) {
          if (xloc) {
            asm volatile("buffer_inv sc0\n\ts_waitcnt vmcnt(0)" ::: "memory");
          } else {
            __threadfence();
          }
        }
      }
      __syncthreads();
    }
    // ---- stage A tile [32 rows x 1280] fp16, XOR-swizzled
    {
      const f16* hsrc = hbuf + (size_t)(s & 1)*262144 + (size_t)grow*1024;
#pragma unroll
      for (int j = 0; j < 16; ++j) {
        int chunk = sseg + 8*j;                        // 16B chunk of h row
        uint4 v = *(const uint4*)(hsrc + chunk*8);
        *(uint4*)(smem + ((srow*2560u + 16u*(u32)chunk) ^ swzr)) = v;
      }
      f16x4 hv;
      hv[0] = (f16)xv0.x; hv[1] = (f16)xv0.y; hv[2] = (f16)xv0.z; hv[3] = (f16)xv0.w;
      *(f16x4*)(smem + ((srow*2560u + 2048u + 8u*(u32)(sseg     )) ^ swzr)) = hv;
      hv[0] = (f16)xv1.x; hv[1] = (f16)xv1.y; hv[2] = (f16)xv1.z; hv[3] = (f16)xv1.w;
      *(f16x4*)(smem + ((srow*2560u + 2048u + 8u*(u32)(sseg +  8)) ^ swzr)) = hv;
      hv[0] = (f16)xv2.x; hv[1] = (f16)xv2.y; hv[2] = (f16)xv2.z; hv[3] = (f16)xv2.w;
      *(f16x4*)(smem + ((srow*2560u + 2048u + 8u*(u32)(sseg + 16)) ^ swzr)) = hv;
      hv[0] = (f16)xv3.x; hv[1] = (f16)xv3.y; hv[2] = (f16)xv3.z; hv[3] = (f16)xv3.w;
      *(f16x4*)(smem + ((srow*2560u + 2048u + 8u*(u32)(sseg + 24)) ^ swzr)) = hv;
      const float* xsrc = x + ((size_t)grow*512 + (size_t)s)*256;
#pragma unroll
      for (int j = 4; j < 8; ++j) {
        int seg = sseg + 8*j;
        float4 v = *(const float4*)(xsrc + seg*4);
        f16x4 h2;
        h2[0] = (f16)v.x; h2[1] = (f16)v.y; h2[2] = (f16)v.z; h2[3] = (f16)v.w;
        *(f16x4*)(smem + ((srow*2560u + 2048u + 8u*(u32)seg) ^ swzr)) = h2;
      }
    }
    __syncthreads();
    // ---- K loop: full K=1280 per wave, 32 z-cols (2 col-frags)
    f32x4 acc00 = {}, acc10 = {}, acc01 = {}, acc11 = {};
#pragma unroll
    for (int kk = 0; kk < 40; ++kk) {
      f16x8 av0 = *(const f16x8*)(smem + ((aoff0 + (u32)kk*64u) ^ aswz));
      f16x8 av1 = *(const f16x8*)(smem + ((aoff1 + (u32)kk*64u) ^ aswz));
      acc00 = __builtin_amdgcn_mfma_f32_16x16x32_f16(av0, Breg[kk][0], acc00, 0, 0, 0);
      acc10 = __builtin_amdgcn_mfma_f32_16x16x32_f16(av1, Breg[kk][0], acc10, 0, 0, 0);
      acc01 = __builtin_amdgcn_mfma_f32_16x16x32_f16(av0, Breg[kk][1], acc01, 0, 0, 0);
      acc11 = __builtin_amdgcn_mfma_f32_16x16x32_f16(av1, Breg[kk][1], acc11, 0, 0, 0);
    }
    // write z to zbuf[gate][row][col] (wave-private region)
    {
      const u32 zb0 = 81920u + (u32)(wv*1024      + l15)*4u;
      const u32 zb1 = 81920u + (u32)(wv*1024 + 16 + l15)*4u;
#pragma unroll
      for (int i = 0; i < 4; ++i) {
        u32 r0 = (u32)(l4*4 + i);
        *(float*)(smem + zb0 + r0*128u)         = acc00[i];
        *(float*)(smem + zb0 + (r0 + 16u)*128u) = acc10[i];
        *(float*)(smem + zb1 + r0*128u)         = acc01[i];
        *(float*)(smem + zb1 + (r0 + 16u)*128u) = acc11[i];
      }
    }
    __syncthreads();
    // ---- gates + c/h update (256 threads, 4 elems each: rows (tid>>5)+e2*8)
    {
      f16* hw = hbuf + (size_t)((s & 1) ^ 1)*262144;
      const int col = tid & 31;
      const int gcol = cg*32 + col;
#pragma unroll
      for (int e2 = 0; e2 < 4; ++e2) {
        const int rr = (tid >> 5) + e2*8;
        const u32 zo = (u32)(rr*128 + col*4);
        float zg = *(const float*)(smem + 81920u +          zo) + bgr;
        float zi = *(const float*)(smem + 81920u + 4096u  + zo) + bir;
        float zf = *(const float*)(smem + 81920u + 8192u  + zo) + bfr;
        float zv = *(const float*)(smem + 81920u + 12288u + zo) + bor;
        float* cp = (float*)(smem + 98304u + (u32)(rr*32 + col)*4u);
        float cv = *cp;
        float gv = tanhfast(zg);
        float iv = sigm(zi);
        float fv = sigm(zf);
        float ov = sigm(zv);
        float cn = gv*iv + cv*fv;
        *cp = cn;
        hw[(size_t)(xg*32 + rr)*1024 + gcol] = (f16)(tanhfast(cn) * ov);
      }
    }
    __syncthreads();   // drains all waves' stores before flag release
    if (tid == 0) {
      if (!xloc) __threadfence();
      __hip_atomic_store(flg + cg, (u32)(s + 1),
                         __ATOMIC_RELAXED, __HIP_MEMORY_SCOPE_AGENT);
    }
  }

  // ---- epilogue: wait for whole group at step 512, then logits = h @ WphT + bp
  if (wv == 0) {
    u32 v = 512u;
    int guard = 0;
    for (;;) {
      if (lane < 32)
        v = __hip_atomic_load(flg + lane, __ATOMIC_RELAXED, __HIP_MEMORY_SCOPE_AGENT);
      if (__all(v >= 512u)) break;
      __builtin_amdgcn_s_sleep(1);
      if (++guard > (1 << 24)) break;
    }
    if (lane == 0) {
      if (xloc) { asm volatile("buffer_inv sc0\n\ts_waitcnt vmcnt(0)" ::: "memory"); }
      else      { __threadfence(); }
    }
  }
  __syncthreads();
  {
#pragma unroll 1
    for (int p = 0; p < 64; ++p) {
      int rowl = wv*8 + (p >> 3);
      int oc   = p & 7;
      const f16* hp = hbuf + (size_t)(xg*32 + rowl)*1024 + lane*16;  // buf 0 = h_T
      const f16* wp = WphT + (size_t)(cg*8 + oc)*1024 + lane*16;
      f16x8 h0 = *(const f16x8*)hp;
      f16x8 h1 = *(const f16x8*)(hp + 8);
      f16x8 w0 = *(const f16x8*)wp;
      f16x8 w1 = *(const f16x8*)(wp + 8);
      float sum = 0.f;
#pragma unroll
      for (int q = 0; q < 8; ++q)
        sum += (float)h0[q]*(float)w0[q] + (float)h1[q]*(float)w1[q];
#pragma unroll
      for (int d = 1; d < 64; d <<= 1) sum += __shfl_xor(sum, d);
      if (lane == 0)
        lg[(size_t)(xg*32 + rowl)*256 + cg*8 + oc] = sum + bpp[cg*8 + oc];
    }
  }
  __syncthreads();   // drain lg stores
  if (tid == 0) {
    if (!xloc) __threadfence();
    __hip_atomic_store(flg + cg, 513u, __ATOMIC_RELAXED, __HIP_MEMORY_SCOPE_AGENT);
  }
  if (wv == 0) {
    u32 v = 513u;
    int guard = 0;
    for (;;) {
      if (lane < 32)
        v = __hip_atomic_load(flg + lane, __ATOMIC_RELAXED, __HIP_MEMORY_SCOPE_AGENT);
      if (__all(v >= 513u)) break;
      __builtin_amdgcn_s_sleep(1);
      if (++guard > (1 << 24)) break;
    }
    if (lane == 0) {
      if (xloc) { asm volatile("buffer_inv sc0\n\ts_waitcnt vmcnt(0)" ::: "memory"); }
      else      { __threadfence(); }
    }
  }
  __syncthreads();
  // ---- softmax: this block handles row xg*32+cg, wave 0 only
  if (tid < 64) {
    int rowg = xg*32 + cg;
    const float* lr = lg + (size_t)rowg*256;
    float v0 = lr[tid], v1 = lr[tid+64], v2 = lr[tid+128], v3 = lr[tid+192];
    float mx = fmaxf(fmaxf(v0, v1), fmaxf(v2, v3));
#pragma unroll
    for (int d = 1; d < 64; d <<= 1) mx = fmaxf(mx, __shfl_xor(mx, d));
    float e0 = __expf(v0-mx), e1 = __expf(v1-mx), e2 = __expf(v2-mx), e3 = __expf(v3-mx);
    float sm = e0+e1+e2+e3;
#pragma unroll
    for (int d = 1; d < 64; d <<= 1) sm += __shfl_xor(sm, d);
    float inv = 1.0f / sm;
    float* orow = out + (size_t)rowg*256;
    orow[tid]      = e0*inv;
    orow[tid+64]   = e1*inv;
    orow[tid+128]  = e2*inv;
    orow[tid+192]  = e3*inv;
  }
}

extern "C" void kernel_launch(void* const* d_in, const int* in_sizes, int n_in,
                              void* d_out, int out_size, void* d_ws, size_t ws_size,
                              hipStream_t stream) {
  (void)in_sizes; (void)n_in; (void)out_size; (void)ws_size;
  const float* x   = (const float*)d_in[0];
  const float* Wgx = (const float*)d_in[1];
  const float* Wgh = (const float*)d_in[2];
  const float* bg  = (const float*)d_in[3];
  const float* Wix = (const float*)d_in[4];
  const float* Wih = (const float*)d_in[5];
  const float* bi  = (const float*)d_in[6];
  const float* Wfx = (const float*)d_in[7];
  const float* Wfh = (const float*)d_in[8];
  const float* bf  = (const float*)d_in[9];
  const float* Wox = (const float*)d_in[10];
  const float* Woh = (const float*)d_in[11];
  const float* bo  = (const float*)d_in[12];
  const float* Wph = (const float*)d_in[13];
  const float* bp  = (const float*)d_in[14];

  char* ws = (char*)d_ws;
  f16*   WT   = (f16*)(ws + WS_WT);
  f16*   WphT = (f16*)(ws + WS_WPHT);
  f16*   hbuf = (f16*)(ws + WS_HBUF);
  float* lg   = (float*)(ws + WS_LG);
  u32*   cnt  = (u32*)(ws + WS_CNT);
  u32*   tick = (u32*)(ws + WS_TICK);

  // h0 = 0 (buffer 0); flags + tickets = 0 (replay-safe)
  hipMemsetAsync(hbuf, 0, 524288, stream);
  hipMemsetAsync(cnt, 0, 2048, stream);

  prep_wt<<<5120, 256, 0, stream>>>(Wgh, Wih, Wfh, Woh, Wgx, Wix, Wfx, Wox, WT);
  prep_wph<<<256, 256, 0, stream>>>(Wph, WphT);
  lstm_main<<<256, 256, 0, stream>>>(x, WT, WphT, hbuf,
                                     bg, bi, bf, bo, bp,
                                     lg, cnt, tick, (float*)d_out);
}

// Round 8
// 4494.452 us; speedup vs baseline: 11.5168x; 1.0676x over previous
//
#include <hip/hip_runtime.h>

// LSTM fused kernel for MI355X (gfx950) — round 8: two interleaved 16-row
// tiles per group to hide inter-block barrier (L3 flag) latency.
// 256 blocks x 256 threads (4 waves, 1 wave/SIMD, 512-reg budget).
// Group = measured XCD (32 blocks); each group owns 32 batch rows split into
// tile A (rows 0-15) and tile B (rows 16-31) — two independent recurrences,
// alternated per block: A1,B1,A2,B2,...  While tile T's flags propagate via
// L3, the block computes the other tile; an early-poll issues the next slot's
// flag loads during the current slot's compute.
// Per slot: z[16,128] = [h_T|x_T] @ W-slice (K=1280), col-split 4 waves
// (32 z-cols each, Breg[40][2]=320 regs weight-stationary, asm-pinned).
// Sync: relaxed agent flags + buffer_inv sc0 acquire (xloc), threadfence
// fallback. Guards 1<<18 (bug -> fast wrong answer, not 600s timeout).
// Workspace (~12.4 MB):
//   WT fp16 [4096][1280] @0   WphT fp16 [256][1024] @10485760
//   hbuf fp16 [2][256][1024] @11010048   lg f32 [256][256] @12058624
//   cnt u32 [8][2][32] @12320768   tick u32 [8] @12322816

typedef _Float16 f16;
typedef _Float16 f16x8 __attribute__((ext_vector_type(8)));
typedef _Float16 f16x4 __attribute__((ext_vector_type(4)));
typedef float f32x4 __attribute__((ext_vector_type(4)));
typedef unsigned int u32;

#define WS_WT    0
#define WS_WPHT  10485760
#define WS_HBUF  11010048
#define WS_LG    12058624
#define WS_CNT   12320768
#define WS_TICK  12322816

__device__ __forceinline__ float sigm(float v) { return 1.0f / (1.0f + __expf(-v)); }
__device__ __forceinline__ float tanhfast(float v) {
  float t = __expf(-2.0f * fabsf(v));
  float r = (1.0f - t) / (1.0f + t);
  return v < 0.0f ? -r : r;
}

// ---------- prep: WT[n][k], n=gate*1024+j (z-col), k<1024 -> Wh[k][j], else Wx[k-1024][j]
__global__ __launch_bounds__(256) void prep_wt(
    const float* __restrict__ Wgh, const float* __restrict__ Wih,
    const float* __restrict__ Wfh, const float* __restrict__ Woh,
    const float* __restrict__ Wgx, const float* __restrict__ Wix,
    const float* __restrict__ Wfx, const float* __restrict__ Wox,
    f16* __restrict__ WT)
{
  __shared__ float tile[32][33];
  int bid = blockIdx.x;
  int gate = bid / 1280;
  int rem  = bid % 1280;
  int jt = rem / 40, kt = rem % 40;
  const float* srcH = (gate==0)?Wgh:(gate==1)?Wih:(gate==2)?Wfh:Woh;
  const float* srcX = (gate==0)?Wgx:(gate==1)?Wix:(gate==2)?Wfx:Wox;
  const float* src = (kt < 32) ? (srcH + (size_t)(kt*32)*1024)
                               : (srcX + (size_t)(kt*32 - 1024)*1024);
  int t = threadIdx.x;
  {
    int jl = t & 31, kg = t >> 5;
#pragma unroll
    for (int it = 0; it < 4; ++it) {
      int kl = kg + it*8;
      tile[kl][jl] = src[(size_t)kl*1024 + jt*32 + jl];
    }
  }
  __syncthreads();
  {
    int kl = t & 31, jg = t >> 5;
#pragma unroll
    for (int it = 0; it < 4; ++it) {
      int jl2 = jg + it*8;
      WT[(size_t)(gate*1024 + jt*32 + jl2)*1280 + kt*32 + kl] = (f16)tile[kl][jl2];
    }
  }
}

// ---------- prep: WphT[oc][k] = W_ph[k][oc], fp16
__global__ __launch_bounds__(256) void prep_wph(const float* __restrict__ Wph,
                                                f16* __restrict__ WphT)
{
  __shared__ float tile[32][33];
  int bid = blockIdx.x;
  int jt = bid & 7, kt = bid >> 3;
  int t = threadIdx.x;
  {
    int jl = t & 31, kg = t >> 5;
#pragma unroll
    for (int it = 0; it < 4; ++it) {
      int kl = kg + it*8;
      tile[kl][jl] = Wph[(size_t)(kt*32 + kl)*256 + jt*32 + jl];
    }
  }
  __syncthreads();
  {
    int kl = t & 31, jg = t >> 5;
#pragma unroll
    for (int it = 0; it < 4; ++it) {
      int jl2 = jg + it*8;
      WphT[(size_t)(jt*32 + jl2)*1024 + kt*32 + kl] = (f16)tile[kl][jl2];
    }
  }
}

// ---------- main persistent LSTM kernel
// LDS: A-tile[2] [16][1280]f16 swizzled @0/@40960, zbuf[2] [4][16][32]f32
//      @81920/@90112, c[2] [16][32]f32 @98304/@100352, bcast @102400.
__global__ __launch_bounds__(256, 1) void lstm_main(
    const float* __restrict__ x, const f16* __restrict__ WT,
    const f16* __restrict__ WphT, f16* __restrict__ hbuf,
    const float* __restrict__ bgp, const float* __restrict__ bip,
    const float* __restrict__ bfp, const float* __restrict__ bop,
    const float* __restrict__ bpp, float* __restrict__ lg,
    u32* __restrict__ cnt, u32* __restrict__ tick, float* __restrict__ out)
{
  __shared__ __align__(16) char smem[102416];
  const int tid  = threadIdx.x;
  const int lane = tid & 63;
  const int wv   = tid >> 6;       // wave = gate (0..3)
  const int l15 = lane & 15, l4 = lane >> 4;

  // ---- measure XCD, take ticket on per-XCD counter
  u32 myxcd;
  asm volatile("s_getreg_b32 %0, hwreg(HW_REG_XCC_ID)" : "=s"(myxcd));
  myxcd &= 7u;
  if (tid == 0) {
    u32 t = __hip_atomic_fetch_add(tick + myxcd, 1u,
                                   __ATOMIC_RELAXED, __HIP_MEMORY_SCOPE_AGENT);
    *(volatile u32*)(smem + 102400) = t;
  }
  if (wv == 0) {
    u32 v = 0;
    int guard = 0;
    for (;;) {
      v = (lane < 8) ? __hip_atomic_load(tick + lane, __ATOMIC_RELAXED,
                                         __HIP_MEMORY_SCOPE_AGENT) : 0u;
      u32 sum = v;
      sum += __shfl_xor(sum, 1);
      sum += __shfl_xor(sum, 2);
      sum += __shfl_xor(sum, 4);
      if (__shfl(sum, 0) == 256u) break;
      __builtin_amdgcn_s_sleep(1);
      if (++guard > (1 << 20)) break;
    }
    int even = __all((lane < 8) ? (v == 32u) : 1);
    if (lane == 0) *(volatile u32*)(smem + 102404) = (u32)even;
  }
  __syncthreads();
  const bool xloc = (*(volatile u32*)(smem + 102404)) != 0u;
  const u32 myticket = *(volatile u32*)(smem + 102400);
  const int xg = xloc ? (int)myxcd    : (blockIdx.x & 7);   // batch-tile group
  const int cg = xloc ? (int)myticket : (blockIdx.x >> 3);  // column slice 0..31
  u32* flg = cnt + xg*64;           // [A flags 0..31][B flags 32..63]

  // ---- weight-stationary B fragments: 40 kk x 2 col-frags = 320 regs, pinned
  f16x8 Breg[40][2];
  {
    const f16* wb0 = WT + (size_t)(wv*1024 + cg*32      + l15)*1280 + l4*8;
    const f16* wb1 = WT + (size_t)(wv*1024 + cg*32 + 16 + l15)*1280 + l4*8;
#pragma unroll
    for (int kk = 0; kk < 40; ++kk) {
      Breg[kk][0] = *(const f16x8*)(wb0 + kk*32);
      asm volatile("" : "+v"(Breg[kk][0]));   // opaque: no remat, stays live
      Breg[kk][1] = *(const f16x8*)(wb1 + kk*32);
      asm volatile("" : "+v"(Breg[kk][1]));
    }
  }

  // per-thread bias (gate phase handles col = tid&31)
  const int bcol = cg*32 + (tid & 31);
  const float bgr = bgp[bcol], bir = bip[bcol], bfr = bfp[bcol], bor = bop[bcol];

  // A-frag addressing: addr = Abase + ((l15*2560 + l4*16 + kk*64) ^ ((l15&7)<<4))
  const u32 aoff0 = (u32)l15*2560u + (u32)(l4*16);
  const u32 aswz  = ((u32)(l15 & 7)) << 4;
  // staging indices: 16 rows x 16 segs
  const int srow = tid >> 4;       // 0..15
  const int sseg = tid & 15;
  const u32 swzr = ((u32)(srow & 7) << 4);

  // zero c (both tiles: 1024 f32)
#pragma unroll
  for (int e = 0; e < 4; ++e)
    *(float*)(smem + 98304 + (tid + e*256)*4) = 0.0f;
  __syncthreads();

  u32 pre = 0xFFFFFFFFu;
  bool preOK = false;

#pragma unroll 1
  for (int slot = 0; slot < 1024; ++slot) {
    const int T = slot & 1, s = slot >> 1;
    const u32 Abase = (u32)T * 40960u;
    const u32 zbase = 81920u + (u32)T * 8192u;
    const u32 cbase = 98304u + (u32)T * 2048u;
    u32* flgT = flg + T*32;
    const int grow = xg*32 + T*16 + srow;

    // ---- x prefetch (rides out during the wait)
    const float* xsrc = x + ((size_t)grow*512 + (size_t)s)*256;
    float4 xv0 = *(const float4*)(xsrc + (sseg     )*4);
    float4 xv1 = *(const float4*)(xsrc + (sseg + 16)*4);
    float4 xv2 = *(const float4*)(xsrc + (sseg + 32)*4);
    float4 xv3 = *(const float4*)(xsrc + (sseg + 48)*4);

    // ---- tile-T barrier: all 32 blocks finished tile-T step s-1
    if (s > 0) {
      if (wv == 0) {
        if (!preOK) {
          const u32 tgt = (u32)s;
          u32 v = tgt;
          int guard = 0;
          for (;;) {
            if (lane < 32)
              v = __hip_atomic_load(flgT + lane, __ATOMIC_RELAXED,
                                    __HIP_MEMORY_SCOPE_AGENT);
            if (__all(v >= tgt)) break;
            __builtin_amdgcn_s_sleep(1);
            if (++guard > (1 << 18)) break;
          }
        }
        if (lane == 0) {
          if (xloc) {
            asm volatile("buffer_inv sc0\n\ts_waitcnt vmcnt(0)" ::: "memory");
          } else {
            __threadfence();
          }
        }
      }
      __syncthreads();
    }
    // ---- stage tile-T A-tile [16 rows x 1280] fp16, XOR-swizzled
    {
      const f16* hsrc = hbuf + (size_t)(s & 1)*262144 + (size_t)grow*1024;
#pragma unroll
      for (int j = 0; j < 8; ++j) {
        int chunk = sseg + 16*j;                       // 16B chunk of h row
        uint4 v = *(const uint4*)(hsrc + chunk*8);
        *(uint4*)(smem + Abase + ((srow*2560u + 16u*(u32)chunk) ^ swzr)) = v;
      }
      f16x4 hv;
      hv[0] = (f16)xv0.x; hv[1] = (f16)xv0.y; hv[2] = (f16)xv0.z; hv[3] = (f16)xv0.w;
      *(f16x4*)(smem + Abase + ((srow*2560u + 2048u + 8u*(u32)(sseg     )) ^ swzr)) = hv;
      hv[0] = (f16)xv1.x; hv[1] = (f16)xv1.y; hv[2] = (f16)xv1.z; hv[3] = (f16)xv1.w;
      *(f16x4*)(smem + Abase + ((srow*2560u + 2048u + 8u*(u32)(sseg + 16)) ^ swzr)) = hv;
      hv[0] = (f16)xv2.x; hv[1] = (f16)xv2.y; hv[2] = (f16)xv2.z; hv[3] = (f16)xv2.w;
      *(f16x4*)(smem + Abase + ((srow*2560u + 2048u + 8u*(u32)(sseg + 32)) ^ swzr)) = hv;
      hv[0] = (f16)xv3.x; hv[1] = (f16)xv3.y; hv[2] = (f16)xv3.z; hv[3] = (f16)xv3.w;
      *(f16x4*)(smem + Abase + ((srow*2560u + 2048u + 8u*(u32)(sseg + 48)) ^ swzr)) = hv;
    }
    __syncthreads();
    // ---- early poll: issue next slot's flag loads now, consume after gates
    {
      const int nT = (slot + 1) & 1, nS = (slot + 1) >> 1;
      pre = 0xFFFFFFFFu;
      if (wv == 0 && nS > 0 && nS < 512 && lane < 32)
        pre = __hip_atomic_load(flg + nT*32 + lane, __ATOMIC_RELAXED,
                                __HIP_MEMORY_SCOPE_AGENT);
    }
    // ---- K loop: full K=1280, 16 rows, 32 z-cols
    f32x4 acc0 = {}, acc1 = {};
#pragma unroll
    for (int kk = 0; kk < 40; ++kk) {
      f16x8 av = *(const f16x8*)(smem + Abase + ((aoff0 + (u32)kk*64u) ^ aswz));
      acc0 = __builtin_amdgcn_mfma_f32_16x16x32_f16(av, Breg[kk][0], acc0, 0, 0, 0);
      acc1 = __builtin_amdgcn_mfma_f32_16x16x32_f16(av, Breg[kk][1], acc1, 0, 0, 0);
    }
    // z write: zbuf[T][gate=wv][row][col]
    {
      const u32 zb0 = zbase + (u32)wv*2048u + (u32)l15*4u;
      const u32 zb1 = zb0 + 64u;                      // col + 16
#pragma unroll
      for (int i = 0; i < 4; ++i) {
        u32 r0 = (u32)(l4*4 + i);
        *(float*)(smem + zb0 + r0*128u) = acc0[i];
        *(float*)(smem + zb1 + r0*128u) = acc1[i];
      }
    }
    __syncthreads();
    // ---- gates + c/h update (256 threads x 2 elems: rows (tid>>5)+e2*8)
    {
      f16* hw = hbuf + (size_t)((s & 1) ^ 1)*262144;
      const int col = tid & 31;
      const int gcol = cg*32 + col;
#pragma unroll
      for (int e2 = 0; e2 < 2; ++e2) {
        const int rr = (tid >> 5) + e2*8;
        const u32 zo = (u32)(rr*128 + col*4);
        float zg = *(const float*)(smem + zbase +         zo) + bgr;
        float zi = *(const float*)(smem + zbase + 2048u + zo) + bir;
        float zf = *(const float*)(smem + zbase + 4096u + zo) + bfr;
        float zv = *(const float*)(smem + zbase + 6144u + zo) + bor;
        float* cp = (float*)(smem + cbase + (u32)(rr*32 + col)*4u);
        float cv = *cp;
        float gv = tanhfast(zg);
        float iv = sigm(zi);
        float fv = sigm(zf);
        float ov = sigm(zv);
        float cn = gv*iv + cv*fv;
        *cp = cn;
        hw[(size_t)(xg*32 + T*16 + rr)*1024 + gcol] = (f16)(tanhfast(cn) * ov);
      }
    }
    __syncthreads();   // drains h stores (vmcnt) before flag release
    if (tid == 0) {
      if (!xloc) __threadfence();
      __hip_atomic_store(flgT + cg, (u32)(s + 1),
                         __ATOMIC_RELAXED, __HIP_MEMORY_SCOPE_AGENT);
    }
    if (wv == 0) {
      const int nS = (slot + 1) >> 1;
      preOK = (nS == 0) || __all(pre >= (u32)nS);
    }
  }

  // ---- epilogue: wait both tiles at 512, logits = h @ WphT + bp
  if (wv == 0) {
    u32 v = 512u;
    int guard = 0;
    for (;;) {
      v = __hip_atomic_load(flg + lane, __ATOMIC_RELAXED,
                            __HIP_MEMORY_SCOPE_AGENT);   // lanes 0-63 = A,B
      if (__all(v >= 512u)) break;
      __builtin_amdgcn_s_sleep(1);
      if (++guard > (1 << 18)) break;
    }
    if (lane == 0) {
      if (xloc) { asm volatile("buffer_inv sc0\n\ts_waitcnt vmcnt(0)" ::: "memory"); }
      else      { __threadfence(); }
    }
  }
  __syncthreads();
  {
#pragma unroll 1
    for (int p = 0; p < 64; ++p) {
      int rowl = wv*8 + (p >> 3);
      int oc   = p & 7;
      const f16* hp = hbuf + (size_t)(xg*32 + rowl)*1024 + lane*16;  // buf 0 = h_T
      const f16* wp = WphT + (size_t)(cg*8 + oc)*1024 + lane*16;
      f16x8 h0 = *(const f16x8*)hp;
      f16x8 h1 = *(const f16x8*)(hp + 8);
      f16x8 w0 = *(const f16x8*)wp;
      f16x8 w1 = *(const f16x8*)(wp + 8);
      float sum = 0.f;
#pragma unroll
      for (int q = 0; q < 8; ++q)
        sum += (float)h0[q]*(float)w0[q] + (float)h1[q]*(float)w1[q];
#pragma unroll
      for (int d = 1; d < 64; d <<= 1) sum += __shfl_xor(sum, d);
      if (lane == 0)
        lg[(size_t)(xg*32 + rowl)*256 + cg*8 + oc] = sum + bpp[cg*8 + oc];
    }
  }
  __syncthreads();   // drain lg stores
  if (tid == 0) {
    if (!xloc) __threadfence();
    __hip_atomic_store(flg + cg, 513u, __ATOMIC_RELAXED, __HIP_MEMORY_SCOPE_AGENT);
  }
  if (wv == 0) {
    u32 v = 513u;
    int guard = 0;
    for (;;) {
      if (lane < 32)
        v = __hip_atomic_load(flg + lane, __ATOMIC_RELAXED, __HIP_MEMORY_SCOPE_AGENT);
      if (__all(v >= 513u)) break;
      __builtin_amdgcn_s_sleep(1);
      if (++guard > (1 << 18)) break;
    }
    if (lane == 0) {
      if (xloc) { asm volatile("buffer_inv sc0\n\ts_waitcnt vmcnt(0)" ::: "memory"); }
      else      { __threadfence(); }
    }
  }
  __syncthreads();
  // ---- softmax: this block handles row xg*32+cg, wave 0 only
  if (tid < 64) {
    int rowg = xg*32 + cg;
    const float* lr = lg + (size_t)rowg*256;
    float v0 = lr[tid], v1 = lr[tid+64], v2 = lr[tid+128], v3 = lr[tid+192];
    float mx = fmaxf(fmaxf(v0, v1), fmaxf(v2, v3));
#pragma unroll
    for (int d = 1; d < 64; d <<= 1) mx = fmaxf(mx, __shfl_xor(mx, d));
    float e0 = __expf(v0-mx), e1 = __expf(v1-mx), e2 = __expf(v2-mx), e3 = __expf(v3-mx);
    float sm = e0+e1+e2+e3;
#pragma unroll
    for (int d = 1; d < 64; d <<= 1) sm += __shfl_xor(sm, d);
    float inv = 1.0f / sm;
    float* orow = out + (size_t)rowg*256;
    orow[tid]      = e0*inv;
    orow[tid+64]   = e1*inv;
    orow[tid+128]  = e2*inv;
    orow[tid+192]  = e3*inv;
  }
}

extern "C" void kernel_launch(void* const* d_in, const int* in_sizes, int n_in,
                              void* d_out, int out_size, void* d_ws, size_t ws_size,
                              hipStream_t stream) {
  (void)in_sizes; (void)n_in; (void)out_size; (void)ws_size;
  const float* x   = (const float*)d_in[0];
  const float* Wgx = (const float*)d_in[1];
  const float* Wgh = (const float*)d_in[2];
  const float* bg  = (const float*)d_in[3];
  const float* Wix = (const float*)d_in[4];
  const float* Wih = (const float*)d_in[5];
  const float* bi  = (const float*)d_in[6];
  const float* Wfx = (const float*)d_in[7];
  const float* Wfh = (const float*)d_in[8];
  const float* bf  = (const float*)d_in[9];
  const float* Wox = (const float*)d_in[10];
  const float* Woh = (const float*)d_in[11];
  const float* bo  = (const float*)d_in[12];
  const float* Wph = (const float*)d_in[13];
  const float* bp  = (const float*)d_in[14];

  char* ws = (char*)d_ws;
  f16*   WT   = (f16*)(ws + WS_WT);
  f16*   WphT = (f16*)(ws + WS_WPHT);
  f16*   hbuf = (f16*)(ws + WS_HBUF);
  float* lg   = (float*)(ws + WS_LG);
  u32*   cnt  = (u32*)(ws + WS_CNT);
  u32*   tick = (u32*)(ws + WS_TICK);

  // h0 = 0 (buffer 0); flags + tickets = 0 (replay-safe)
  hipMemsetAsync(hbuf, 0, 524288, stream);
  hipMemsetAsync(cnt, 0, 2048 + 64, stream);

  prep_wt<<<5120, 256, 0, stream>>>(Wgh, Wih, Wfh, Woh, Wgx, Wix, Wfx, Wox, WT);
  prep_wph<<<256, 256, 0, stream>>>(Wph, WphT);
  lstm_main<<<256, 256, 0, stream>>>(x, WT, WphT, hbuf,
                                     bg, bi, bf, bo, bp,
                                     lg, cnt, tick, (float*)d_out);
}

// Round 9
// 3459.196 us; speedup vs baseline: 14.9635x; 1.2993x over previous
//
#include <hip/hip_runtime.h>

// LSTM fused kernel for MI355X (gfx950) — round 9: 8 waves x 16 z-cols
// (Breg 160 VGPR -> 2 waves/SIMD TLP) + round-8 tile interleave & sync.
// 256 blocks x 512 threads. Group = measured XCD (32 blocks); group owns 32
// batch rows split into tiles A/B (16 rows each), alternated per slot.
// Per slot: z[16,128] = [h_T|x_T] @ W-slice (K=1280), col-split 8 waves
// (wave w: gate w>>1, 16-col half w&1; Breg[40]=160 VGPR weight-stationary).
// Sync: relaxed agent flags + buffer_inv sc0 acquire (xloc path), early-poll
// of next slot's flags during compute; threadfence fallback. Guards 1<<18.
// Workspace (~12.4 MB):
//   WT fp16 [4096][1280] @0   WphT fp16 [256][1024] @10485760
//   hbuf fp16 [2][256][1024] @11010048   lg f32 [256][256] @12058624
//   cnt u32 [8][2][32] @12320768   tick u32 [8] @12322816

typedef _Float16 f16;
typedef _Float16 f16x8 __attribute__((ext_vector_type(8)));
typedef _Float16 f16x4 __attribute__((ext_vector_type(4)));
typedef float f32x4 __attribute__((ext_vector_type(4)));
typedef unsigned int u32;

#define WS_WT    0
#define WS_WPHT  10485760
#define WS_HBUF  11010048
#define WS_LG    12058624
#define WS_CNT   12320768
#define WS_TICK  12322816

__device__ __forceinline__ float sigm(float v) { return 1.0f / (1.0f + __expf(-v)); }
__device__ __forceinline__ float tanhfast(float v) {
  float t = __expf(-2.0f * fabsf(v));
  float r = (1.0f - t) / (1.0f + t);
  return v < 0.0f ? -r : r;
}

// ---------- prep: WT[n][k], n=gate*1024+j (z-col), k<1024 -> Wh[k][j], else Wx[k-1024][j]
__global__ __launch_bounds__(256) void prep_wt(
    const float* __restrict__ Wgh, const float* __restrict__ Wih,
    const float* __restrict__ Wfh, const float* __restrict__ Woh,
    const float* __restrict__ Wgx, const float* __restrict__ Wix,
    const float* __restrict__ Wfx, const float* __restrict__ Wox,
    f16* __restrict__ WT)
{
  __shared__ float tile[32][33];
  int bid = blockIdx.x;
  int gate = bid / 1280;
  int rem  = bid % 1280;
  int jt = rem / 40, kt = rem % 40;
  const float* srcH = (gate==0)?Wgh:(gate==1)?Wih:(gate==2)?Wfh:Woh;
  const float* srcX = (gate==0)?Wgx:(gate==1)?Wix:(gate==2)?Wfx:Wox;
  const float* src = (kt < 32) ? (srcH + (size_t)(kt*32)*1024)
                               : (srcX + (size_t)(kt*32 - 1024)*1024);
  int t = threadIdx.x;
  {
    int jl = t & 31, kg = t >> 5;
#pragma unroll
    for (int it = 0; it < 4; ++it) {
      int kl = kg + it*8;
      tile[kl][jl] = src[(size_t)kl*1024 + jt*32 + jl];
    }
  }
  __syncthreads();
  {
    int kl = t & 31, jg = t >> 5;
#pragma unroll
    for (int it = 0; it < 4; ++it) {
      int jl2 = jg + it*8;
      WT[(size_t)(gate*1024 + jt*32 + jl2)*1280 + kt*32 + kl] = (f16)tile[kl][jl2];
    }
  }
}

// ---------- prep: WphT[oc][k] = W_ph[k][oc], fp16
__global__ __launch_bounds__(256) void prep_wph(const float* __restrict__ Wph,
                                                f16* __restrict__ WphT)
{
  __shared__ float tile[32][33];
  int bid = blockIdx.x;
  int jt = bid & 7, kt = bid >> 3;
  int t = threadIdx.x;
  {
    int jl = t & 31, kg = t >> 5;
#pragma unroll
    for (int it = 0; it < 4; ++it) {
      int kl = kg + it*8;
      tile[kl][jl] = Wph[(size_t)(kt*32 + kl)*256 + jt*32 + jl];
    }
  }
  __syncthreads();
  {
    int kl = t & 31, jg = t >> 5;
#pragma unroll
    for (int it = 0; it < 4; ++it) {
      int jl2 = jg + it*8;
      WphT[(size_t)(jt*32 + jl2)*1024 + kt*32 + kl] = (f16)tile[kl][jl2];
    }
  }
}

// ---------- main persistent LSTM kernel
// LDS: A-tile[2] [16][1280]f16 swizzled @0/@40960, zbuf[2] [4][16][32]f32
//      @81920/@90112, c[2] [16][32]f32 @98304/@100352, bcast @102400.
__global__ __launch_bounds__(512, 2) void lstm_main(
    const float* __restrict__ x, const f16* __restrict__ WT,
    const f16* __restrict__ WphT, f16* __restrict__ hbuf,
    const float* __restrict__ bgp, const float* __restrict__ bip,
    const float* __restrict__ bfp, const float* __restrict__ bop,
    const float* __restrict__ bpp, float* __restrict__ lg,
    u32* __restrict__ cnt, u32* __restrict__ tick, float* __restrict__ out)
{
  __shared__ __align__(16) char smem[102416];
  const int tid  = threadIdx.x;
  const int lane = tid & 63;
  const int wv   = tid >> 6;       // 8 waves: gate = wv>>1, half = wv&1
  const int gate = wv >> 1;
  const int half = wv & 1;
  const int l15 = lane & 15, l4 = lane >> 4;

  // ---- measure XCD, take ticket on per-XCD counter
  u32 myxcd;
  asm volatile("s_getreg_b32 %0, hwreg(HW_REG_XCC_ID)" : "=s"(myxcd));
  myxcd &= 7u;
  if (tid == 0) {
    u32 t = __hip_atomic_fetch_add(tick + myxcd, 1u,
                                   __ATOMIC_RELAXED, __HIP_MEMORY_SCOPE_AGENT);
    *(volatile u32*)(smem + 102400) = t;
  }
  if (wv == 0) {
    u32 v = 0;
    int guard = 0;
    for (;;) {
      v = (lane < 8) ? __hip_atomic_load(tick + lane, __ATOMIC_RELAXED,
                                         __HIP_MEMORY_SCOPE_AGENT) : 0u;
      u32 sum = v;
      sum += __shfl_xor(sum, 1);
      sum += __shfl_xor(sum, 2);
      sum += __shfl_xor(sum, 4);
      if (__shfl(sum, 0) == 256u) break;
      __builtin_amdgcn_s_sleep(1);
      if (++guard > (1 << 20)) break;
    }
    int even = __all((lane < 8) ? (v == 32u) : 1);
    if (lane == 0) *(volatile u32*)(smem + 102404) = (u32)even;
  }
  __syncthreads();
  const bool xloc = (*(volatile u32*)(smem + 102404)) != 0u;
  const u32 myticket = *(volatile u32*)(smem + 102400);
  const int xg = xloc ? (int)myxcd    : (blockIdx.x & 7);   // batch-tile group
  const int cg = xloc ? (int)myticket : (blockIdx.x >> 3);  // column slice 0..31
  u32* flg = cnt + xg*64;           // [A flags 0..31][B flags 32..63]

  // ---- weight-stationary B fragments: 40 x f16x8 = 160 VGPR, pinned
  f16x8 Breg[40];
  {
    const int ncol = gate*1024 + cg*32 + half*16 + l15;    // global z-col
    const f16* wb = WT + (size_t)ncol*1280 + l4*8;
#pragma unroll
    for (int kk = 0; kk < 40; ++kk) {
      Breg[kk] = *(const f16x8*)(wb + kk*32);
      asm volatile("" : "+v"(Breg[kk]));   // opaque: no remat, stays live
    }
  }

  // per-thread bias (gate phase handles col = tid&31)
  const int bcol = cg*32 + (tid & 31);
  const float bgr = bgp[bcol], bir = bip[bcol], bfr = bfp[bcol], bor = bop[bcol];

  // A-frag addressing: addr = Abase + ((l15*2560 + l4*16 + kk*64) ^ ((l15&7)<<4))
  const u32 aoff0 = (u32)l15*2560u + (u32)(l4*16);
  const u32 aswz  = ((u32)(l15 & 7)) << 4;
  // staging indices: 16 rows x 32 segs (512 threads)
  const int srow = tid >> 5;       // 0..15
  const int sseg = tid & 31;       // 0..31
  const u32 swzr = ((u32)(srow & 7) << 4);

  // zero c (both tiles: 1024 f32 / 512 thr = 2 each)
  *(float*)(smem + 98304 + tid*4) = 0.0f;
  *(float*)(smem + 98304 + (tid + 512)*4) = 0.0f;
  __syncthreads();

  u32 pre = 0xFFFFFFFFu;
  bool preOK = false;

#pragma unroll 1
  for (int slot = 0; slot < 1024; ++slot) {
    const int T = slot & 1, s = slot >> 1;
    const u32 Abase = (u32)T * 40960u;
    const u32 zbase = 81920u + (u32)T * 8192u;
    const u32 cbase = 98304u + (u32)T * 2048u;
    u32* flgT = flg + T*32;
    const int grow = xg*32 + T*16 + srow;

    // ---- x prefetch (rides out during the wait): 2 float4/thread
    const float* xsrc = x + ((size_t)grow*512 + (size_t)s)*256;
    float4 xv0 = *(const float4*)(xsrc + (sseg     )*4);
    float4 xv1 = *(const float4*)(xsrc + (sseg + 32)*4);

    // ---- tile-T barrier: all 32 blocks finished tile-T step s-1
    if (s > 0) {
      if (wv == 0) {
        if (!preOK) {
          const u32 tgt = (u32)s;
          u32 v = tgt;
          int guard = 0;
          for (;;) {
            if (lane < 32)
              v = __hip_atomic_load(flgT + lane, __ATOMIC_RELAXED,
                                    __HIP_MEMORY_SCOPE_AGENT);
            if (__all(v >= tgt)) break;
            __builtin_amdgcn_s_sleep(1);
            if (++guard > (1 << 18)) break;
          }
        }
        if (lane == 0) {
          if (xloc) {
            asm volatile("buffer_inv sc0\n\ts_waitcnt vmcnt(0)" ::: "memory");
          } else {
            __threadfence();
          }
        }
      }
      __syncthreads();
    }
    // ---- stage tile-T A-tile [16 rows x 1280] fp16, XOR-swizzled
    {
      const f16* hsrc = hbuf + (size_t)(s & 1)*262144 + (size_t)grow*1024;
#pragma unroll
      for (int j = 0; j < 4; ++j) {
        int chunk = sseg + 32*j;                       // 16B chunk of h row
        uint4 v = *(const uint4*)(hsrc + chunk*8);
        *(uint4*)(smem + Abase + ((srow*2560u + 16u*(u32)chunk) ^ swzr)) = v;
      }
      f16x4 hv;
      hv[0] = (f16)xv0.x; hv[1] = (f16)xv0.y; hv[2] = (f16)xv0.z; hv[3] = (f16)xv0.w;
      *(f16x4*)(smem + Abase + ((srow*2560u + 2048u + 8u*(u32)(sseg     )) ^ swzr)) = hv;
      hv[0] = (f16)xv1.x; hv[1] = (f16)xv1.y; hv[2] = (f16)xv1.z; hv[3] = (f16)xv1.w;
      *(f16x4*)(smem + Abase + ((srow*2560u + 2048u + 8u*(u32)(sseg + 32)) ^ swzr)) = hv;
    }
    __syncthreads();
    // ---- early poll: issue next slot's flag loads now, consume after gates
    {
      const int nT = (slot + 1) & 1, nS = (slot + 1) >> 1;
      pre = 0xFFFFFFFFu;
      if (wv == 0 && nS > 0 && nS < 512 && lane < 32)
        pre = __hip_atomic_load(flg + nT*32 + lane, __ATOMIC_RELAXED,
                                __HIP_MEMORY_SCOPE_AGENT);
    }
    // ---- K loop: full K=1280, 16 rows, 16 z-cols per wave
    f32x4 acc = {};
#pragma unroll
    for (int kk = 0; kk < 40; ++kk) {
      f16x8 av = *(const f16x8*)(smem + Abase + ((aoff0 + (u32)kk*64u) ^ aswz));
      acc = __builtin_amdgcn_mfma_f32_16x16x32_f16(av, Breg[kk], acc, 0, 0, 0);
    }
    // z write: zbuf[T][gate][row][col], this wave's 16-col half
    {
      const u32 zb = zbase + (u32)gate*2048u + (u32)(half*16 + l15)*4u;
#pragma unroll
      for (int i = 0; i < 4; ++i) {
        u32 r0 = (u32)(l4*4 + i);
        *(float*)(smem + zb + r0*128u) = acc[i];
      }
    }
    __syncthreads();
    // ---- gates + c/h update (512 threads x 1 elem: row tid>>5, col tid&31)
    {
      f16* hw = hbuf + (size_t)((s & 1) ^ 1)*262144;
      const int row = tid >> 5, col = tid & 31;
      const int gcol = cg*32 + col;
      const u32 zo = (u32)(row*128 + col*4);
      float zg = *(const float*)(smem + zbase +         zo) + bgr;
      float zi = *(const float*)(smem + zbase + 2048u + zo) + bir;
      float zf = *(const float*)(smem + zbase + 4096u + zo) + bfr;
      float zv = *(const float*)(smem + zbase + 6144u + zo) + bor;
      float* cp = (float*)(smem + cbase + (u32)(row*32 + col)*4u);
      float cv = *cp;
      float gv = tanhfast(zg);
      float iv = sigm(zi);
      float fv = sigm(zf);
      float ov = sigm(zv);
      float cn = gv*iv + cv*fv;
      *cp = cn;
      hw[(size_t)(xg*32 + T*16 + row)*1024 + gcol] = (f16)(tanhfast(cn) * ov);
    }
    __syncthreads();   // drains h stores (vmcnt) before flag release
    if (tid == 0) {
      if (!xloc) __threadfence();
      __hip_atomic_store(flgT + cg, (u32)(s + 1),
                         __ATOMIC_RELAXED, __HIP_MEMORY_SCOPE_AGENT);
    }
    if (wv == 0) {
      const int nS = (slot + 1) >> 1;
      preOK = (nS == 0) || __all(pre >= (u32)nS);
    }
  }

  // ---- epilogue: wait both tiles at 512, logits = h @ WphT + bp
  if (wv == 0) {
    u32 v = 512u;
    int guard = 0;
    for (;;) {
      v = __hip_atomic_load(flg + lane, __ATOMIC_RELAXED,
                            __HIP_MEMORY_SCOPE_AGENT);   // lanes 0-63 = A,B
      if (__all(v >= 512u)) break;
      __builtin_amdgcn_s_sleep(1);
      if (++guard > (1 << 18)) break;
    }
    if (lane == 0) {
      if (xloc) { asm volatile("buffer_inv sc0\n\ts_waitcnt vmcnt(0)" ::: "memory"); }
      else      { __threadfence(); }
    }
  }
  __syncthreads();
  {
#pragma unroll 1
    for (int p = 0; p < 32; ++p) {
      int rowl = wv*4 + (p >> 3);
      int oc   = p & 7;
      const f16* hp = hbuf + (size_t)(xg*32 + rowl)*1024 + lane*16;  // buf 0 = h_T
      const f16* wp = WphT + (size_t)(cg*8 + oc)*1024 + lane*16;
      f16x8 h0 = *(const f16x8*)hp;
      f16x8 h1 = *(const f16x8*)(hp + 8);
      f16x8 w0 = *(const f16x8*)wp;
      f16x8 w1 = *(const f16x8*)(wp + 8);
      float sum = 0.f;
#pragma unroll
      for (int q = 0; q < 8; ++q)
        sum += (float)h0[q]*(float)w0[q] + (float)h1[q]*(float)w1[q];
#pragma unroll
      for (int d = 1; d < 64; d <<= 1) sum += __shfl_xor(sum, d);
      if (lane == 0)
        lg[(size_t)(xg*32 + rowl)*256 + cg*8 + oc] = sum + bpp[cg*8 + oc];
    }
  }
  __syncthreads();   // drain lg stores
  if (tid == 0) {
    if (!xloc) __threadfence();
    __hip_atomic_store(flg + cg, 513u, __ATOMIC_RELAXED, __HIP_MEMORY_SCOPE_AGENT);
  }
  if (wv == 0) {
    u32 v = 513u;
    int guard = 0;
    for (;;) {
      if (lane < 32)
        v = __hip_atomic_load(flg + lane, __ATOMIC_RELAXED, __HIP_MEMORY_SCOPE_AGENT);
      if (__all(v >= 513u)) break;
      __builtin_amdgcn_s_sleep(1);
      if (++guard > (1 << 18)) break;
    }
    if (lane == 0) {
      if (xloc) { asm volatile("buffer_inv sc0\n\ts_waitcnt vmcnt(0)" ::: "memory"); }
      else      { __threadfence(); }
    }
  }
  __syncthreads();
  // ---- softmax: this block handles row xg*32+cg, wave 0 only
  if (tid < 64) {
    int rowg = xg*32 + cg;
    const float* lr = lg + (size_t)rowg*256;
    float v0 = lr[tid], v1 = lr[tid+64], v2 = lr[tid+128], v3 = lr[tid+192];
    float mx = fmaxf(fmaxf(v0, v1), fmaxf(v2, v3));
#pragma unroll
    for (int d = 1; d < 64; d <<= 1) mx = fmaxf(mx, __shfl_xor(mx, d));
    float e0 = __expf(v0-mx), e1 = __expf(v1-mx), e2 = __expf(v2-mx), e3 = __expf(v3-mx);
    float sm = e0+e1+e2+e3;
#pragma unroll
    for (int d = 1; d < 64; d <<= 1) sm += __shfl_xor(sm, d);
    float inv = 1.0f / sm;
    float* orow = out + (size_t)rowg*256;
    orow[tid]      = e0*inv;
    orow[tid+64]   = e1*inv;
    orow[tid+128]  = e2*inv;
    orow[tid+192]  = e3*inv;
  }
}

extern "C" void kernel_launch(void* const* d_in, const int* in_sizes, int n_in,
                              void* d_out, int out_size, void* d_ws, size_t ws_size,
                              hipStream_t stream) {
  (void)in_sizes; (void)n_in; (void)out_size; (void)ws_size;
  const float* x   = (const float*)d_in[0];
  const float* Wgx = (const float*)d_in[1];
  const float* Wgh = (const float*)d_in[2];
  const float* bg  = (const float*)d_in[3];
  const float* Wix = (const float*)d_in[4];
  const float* Wih = (const float*)d_in[5];
  const float* bi  = (const float*)d_in[6];
  const float* Wfx = (const float*)d_in[7];
  const float* Wfh = (const float*)d_in[8];
  const float* bf  = (const float*)d_in[9];
  const float* Wox = (const float*)d_in[10];
  const float* Woh = (const float*)d_in[11];
  const float* bo  = (const float*)d_in[12];
  const float* Wph = (const float*)d_in[13];
  const float* bp  = (const float*)d_in[14];

  char* ws = (char*)d_ws;
  f16*   WT   = (f16*)(ws + WS_WT);
  f16*   WphT = (f16*)(ws + WS_WPHT);
  f16*   hbuf = (f16*)(ws + WS_HBUF);
  float* lg   = (float*)(ws + WS_LG);
  u32*   cnt  = (u32*)(ws + WS_CNT);
  u32*   tick = (u32*)(ws + WS_TICK);

  // h0 = 0 (buffer 0); flags + tickets = 0 (replay-safe)
  hipMemsetAsync(hbuf, 0, 524288, stream);
  hipMemsetAsync(cnt, 0, 2048 + 64, stream);

  prep_wt<<<5120, 256, 0, stream>>>(Wgh, Wih, Wfh, Woh, Wgx, Wix, Wfx, Wox, WT);
  prep_wph<<<256, 256, 0, stream>>>(Wph, WphT);
  lstm_main<<<256, 512, 0, stream>>>(x, WT, WphT, hbuf,
                                     bg, bi, bf, bo, bp,
                                     lg, cnt, tick, (float*)d_out);
}